// Round 14
// baseline (1453.524 us; speedup 1.0000x reference)
//
#include <hip/hip_runtime.h>
#include <hip/hip_bf16.h>
#include <math.h>

// ---------------- problem constants ----------------
#define B 2
#define S 1024
#define D 1024
#define H 16
#define DH 64
#define NL 6
#define GH 64
#define NP 16
#define V 32000
#define FF 2730
#define FFP 2752   // FF padded to multiple of 64
#define M (B*S)    // 2048 rows

typedef float fv4 __attribute__((ext_vector_type(4)));
typedef short bf16x8 __attribute__((ext_vector_type(8)));       // 8 bf16 = 4 VGPRs
typedef unsigned short us4 __attribute__((ext_vector_type(4))); // 4 bf16 = 8 bytes
typedef unsigned short us;

#define MFMA16 __builtin_amdgcn_mfma_f32_16x16x32_bf16
#define G2L16(g, l) __builtin_amdgcn_global_load_lds( \
    (const __attribute__((address_space(1))) void*)(g), \
    (__attribute__((address_space(3))) void*)(l), 16, 0, 0)

__device__ __forceinline__ us f2bf(float f) {
  union { float f; unsigned u; } v; v.f = f;
  unsigned r = v.u + 0x7FFFu + ((v.u >> 16) & 1u);   // RNE
  return (us)(r >> 16);
}
__device__ __forceinline__ float bf2f(us h) {
  union { unsigned u; float f; } v; v.u = ((unsigned)h) << 16;
  return v.f;
}

template<int N> __device__ __forceinline__ void waitcnt_vm() {
  if constexpr (N == 0)      asm volatile("s_waitcnt vmcnt(0)" ::: "memory");
  else if constexpr (N == 4) asm volatile("s_waitcnt vmcnt(4)" ::: "memory");
  else if constexpr (N == 8) asm volatile("s_waitcnt vmcnt(8)" ::: "memory");
  else if constexpr (N == 6) asm volatile("s_waitcnt vmcnt(6)" ::: "memory");
}

// m204 bijective XCD swizzle
__device__ __forceinline__ int xcd_remap(int flat, int nwg) {
  int q = nwg >> 3, r = nwg & 7;
  int xcd = flat & 7, idx = flat >> 3;
  return (xcd < r) ? (xcd * (q + 1) + idx) : (r * (q + 1) + (xcd - r) * q + idx);
}

// ======================================================================
// embed
// ======================================================================
__global__ __launch_bounds__(256) void k_embed(const int* __restrict__ ids,
                                               const float* __restrict__ emb,
                                               const float* __restrict__ winit,
                                               float* __restrict__ x) {
  int m = blockIdx.x, t = threadIdx.x;
  int id = ids[m];
  fv4 a = *(const fv4*)(emb + (size_t)id * D + 4*t);
  fv4 w = *(const fv4*)(winit + 4*t);
  *(fv4*)(x + (size_t)m * D + 4*t) = a + w;
}

// ======================================================================
// rope tables
// ======================================================================
__global__ void k_rope_tables(float* __restrict__ cosT, float* __restrict__ sinT) {
  int idx = blockIdx.x * blockDim.x + threadIdx.x;
  if (idx >= S * 32) return;
  int s = idx >> 5, f = idx & 31;
  float inv = powf(10000.0f, -2.0f * (float)f / (float)DH);
  float ang = (float)s * inv;
  cosT[idx] = cosf(ang);
  sinT[idx] = sinf(ang);
}

// ======================================================================
// Mp[h][d][e] -> bf16
// ======================================================================
__global__ __launch_bounds__(256) void k_mp(const float* __restrict__ pers,
                                            us* __restrict__ Mp) {
  int h = blockIdx.x, t = threadIdx.x;
  __shared__ float p[NP][DH];
  for (int i = t; i < NP * DH; i += 256) {
    int n = i / DH, dh = i % DH;
    p[n][dh] = pers[(size_t)n * D + h * DH + dh];
  }
  __syncthreads();
  for (int i = t; i < DH * DH; i += 256) {
    int d = i / DH, e = i % DH;
    float s = 0.f;
#pragma unroll
    for (int n = 0; n < NP; n++) s += p[n][d] * p[n][e];
    Mp[(size_t)h * DH * DH + i] = f2bf(s);
  }
}

// ======================================================================
// rmsnorm rows of D -> bf16 only
// ======================================================================
__global__ __launch_bounds__(256) void k_rms(const float* __restrict__ in,
                                             const float* __restrict__ w,
                                             us* __restrict__ outb) {
  int m = blockIdx.x, t = threadIdx.x;
  fv4 v = *(const fv4*)(in + (size_t)m * D + 4*t);
  float ss = v[0]*v[0] + v[1]*v[1] + v[2]*v[2] + v[3]*v[3];
#pragma unroll
  for (int off = 32; off > 0; off >>= 1) ss += __shfl_down(ss, off);
  __shared__ float buf[4];
  if ((t & 63) == 0) buf[t >> 6] = ss;
  __syncthreads();
  float tot = buf[0] + buf[1] + buf[2] + buf[3];
  float r = rsqrtf(tot * (1.0f / (float)D) + 1e-6f);
  fv4 wv = *(const fv4*)(w + 4*t);
  fv4 res = v * r * wv;
  us4 o; o[0]=f2bf(res[0]); o[1]=f2bf(res[1]); o[2]=f2bf(res[2]); o[3]=f2bf(res[3]);
  *(us4*)(outb + (size_t)m * D + 4*t) = o;
}

// ======================================================================
// FUSED rmsnorm + gamma gate (norm1 path), bf16 out only.
// ======================================================================
__global__ __launch_bounds__(256) void k_rmsg(const float* __restrict__ in,
                                              const float* __restrict__ w,
                                              const float* __restrict__ w1,
                                              const float* __restrict__ w2,
                                              us* __restrict__ outb,
                                              float* __restrict__ gko) {
  int m = blockIdx.x, t = threadIdx.x;
  __shared__ float hrow[D];
  __shared__ float buf[4];
  __shared__ float part[4][64];
  fv4 v = *(const fv4*)(in + (size_t)m * D + 4*t);
  float ss = v[0]*v[0] + v[1]*v[1] + v[2]*v[2] + v[3]*v[3];
#pragma unroll
  for (int off = 32; off > 0; off >>= 1) ss += __shfl_down(ss, off);
  if ((t & 63) == 0) buf[t >> 6] = ss;
  __syncthreads();
  float tot = buf[0] + buf[1] + buf[2] + buf[3];
  float r = rsqrtf(tot * (1.0f / (float)D) + 1e-6f);
  fv4 wv = *(const fv4*)(w + 4*t);
  fv4 res = v * r * wv;
  us4 o; o[0]=f2bf(res[0]); o[1]=f2bf(res[1]); o[2]=f2bf(res[2]); o[3]=f2bf(res[3]);
  *(us4*)(outb + (size_t)m * D + 4*t) = o;
  *(fv4*)&hrow[4*t] = res;
  __syncthreads();
  int oo = t & 63, seg = t >> 6;
  const float* wr = w1 + (size_t)oo * D + seg * 256;
  const float* hr = hrow + seg * 256;
  float acc = 0.f;
  for (int j = 0; j < 256; j += 4) {
    fv4 wv4 = *(const fv4*)(wr + j);
    acc += wv4[0]*hr[j] + wv4[1]*hr[j+1] + wv4[2]*hr[j+2] + wv4[3]*hr[j+3];
  }
  part[seg][oo] = acc;
  __syncthreads();
  if (t < 64) {
    float dot = part[0][t] + part[1][t] + part[2][t] + part[3][t];
    float sv = dot / (1.f + expf(-dot));
    float val = sv * w2[t];
#pragma unroll
    for (int off = 32; off > 0; off >>= 1) val += __shfl_down(val, off);
    if (t == 0) gko[m] = 1.f / (1.f + expf(-val));
  }
}

// ======================================================================
// flat f32 -> bf16 convert
// ======================================================================
__global__ __launch_bounds__(256) void k_cvt(const float* __restrict__ src,
                                             us* __restrict__ dst, int n) {
  for (size_t i = ((size_t)blockIdx.x * 256 + threadIdx.x) * 4; i < (size_t)n;
       i += (size_t)gridDim.x * 1024) {
    fv4 v = *(const fv4*)(src + i);
    us4 o; o[0]=f2bf(v[0]); o[1]=f2bf(v[1]); o[2]=f2bf(v[2]); o[3]=f2bf(v[3]);
    *(us4*)(dst + i) = o;
  }
}

// ======================================================================
// per-layer weight conversion, single launch
// ======================================================================
#define CVT_N1 786432   // 3*D*D/4
#define CVT_N2 262144   // D*D/4
#define CVT_N3 698880   // FF*D/4
#define CVT_N4 698880
#define CVT_N5 704512   // D * FFP/4
__global__ __launch_bounds__(256) void k_cvtw(const float* __restrict__ s1,
                                              const float* __restrict__ s2,
                                              const float* __restrict__ s3,
                                              const float* __restrict__ s4,
                                              const float* __restrict__ s5,
                                              us* __restrict__ d1, us* __restrict__ d2,
                                              us* __restrict__ d3, us* __restrict__ d4,
                                              us* __restrict__ d5) {
  const int TOT = CVT_N1 + CVT_N2 + CVT_N3 + CVT_N4 + CVT_N5;
  for (int i = blockIdx.x * 256 + threadIdx.x; i < TOT; i += gridDim.x * 256) {
    const float* s; us* d; int j = i;
    if (j < CVT_N1) { s = s1; d = d1; }
    else if ((j -= CVT_N1) < CVT_N2) { s = s2; d = d2; }
    else if ((j -= CVT_N2) < CVT_N3) { s = s3; d = d3; }
    else if ((j -= CVT_N3) < CVT_N4) { s = s4; d = d4; }
    else {
      j -= CVT_N4;
      int r = j / (FFP/4), c = (j % (FFP/4)) * 4;
      us4 o;
#pragma unroll
      for (int q = 0; q < 4; q++) {
        int cc = c + q;
        o[q] = (cc < FF) ? f2bf(s5[(size_t)r * FF + cc]) : (us)0;
      }
      *(us4*)&d5[(size_t)r * FFP + c] = o;
      continue;
    }
    fv4 v = *(const fv4*)(s + (size_t)4 * j);
    us4 o; o[0]=f2bf(v[0]); o[1]=f2bf(v[1]); o[2]=f2bf(v[2]); o[3]=f2bf(v[3]);
    *(us4*)&d[(size_t)4 * j] = o;
  }
}

// ======================================================================
// PIPELINED bf16 MFMA GEMM (g8 discipline).
// ======================================================================
template<int ACW, int BCW>
__device__ __forceinline__ void pg_stage(const us* __restrict__ A,
                                         const us* __restrict__ W,
                                         us* bufA, us* bufB,
                                         int m0, int n0, int Nn, int Kk,
                                         int tile, int w, int lane, int lr, int sx) {
#pragma unroll
  for (int i = 0; i < ACW; i++) {
    int chunk = w * ACW + i;
    G2L16(A + (size_t)(m0 + chunk*8 + lr) * Kk + tile*64 + sx, bufA + chunk*512 + lane*8);
  }
#pragma unroll
  for (int i = 0; i < BCW; i++) {
    int chunk = w * BCW + i;
    int wrow = n0 + chunk*8 + lr;
    if (wrow >= Nn) wrow = Nn - 1;
    G2L16(W + (size_t)wrow * Kk + tile*64 + sx, bufB + chunk*512 + lane*8);
  }
}

template<int EPI, int BM, int BN>
__global__ __launch_bounds__(256) void k_pgemm(const us* __restrict__ A,
                                               const us* __restrict__ W,
                                               float* __restrict__ C,
                                               int Nn, int Kk) {
  constexpr int FM = BM / 32, FN = BN / 32;
  constexpr int ACW = BM / 32, BCW = BN / 32;
  constexpr int L = ACW + BCW;
  __shared__ __attribute__((aligned(16))) us lds[2][(BM + BN) * 64];
  int t = threadIdx.x, lane = t & 63, w = t >> 6;
  int l16 = lane & 15, lkb = lane >> 4, lr = lane >> 3;
  int sx = ((lane & 7) ^ lr) * 8;
  int sw = l16 & 7;
  int gx = gridDim.x, nwg = gx * gridDim.y;
  int nf = xcd_remap(blockIdx.y * gx + blockIdx.x, nwg);
  int m0 = (nf % gx) * BM, n0 = (nf / gx) * BN;
  int wr = w >> 1, wc = w & 1;
  int NK = Kk >> 6;

  pg_stage<ACW,BCW>(A, W, lds[0], lds[0] + BM*64, m0, n0, Nn, Kk, 0, w, lane, lr, sx);
  pg_stage<ACW,BCW>(A, W, lds[1], lds[1] + BM*64, m0, n0, Nn, Kk, 1, w, lane, lr, sx);

  fv4 acc[FM][FN] = {};
  for (int T = 0; T < NK; T++) {
    if (T == NK - 1) waitcnt_vm<0>(); else waitcnt_vm<L>();
    __builtin_amdgcn_s_barrier();
    const us* bufA = lds[T & 1];
    const us* bufB = bufA + BM*64;
    bf16x8 af[2][FM], bfh[2][FN];
#pragma unroll
    for (int kk = 0; kk < 2; kk++) {
#pragma unroll
      for (int i = 0; i < FM; i++)
        af[kk][i] = *(const bf16x8*)&bufA[(wr*(BM/2) + i*16 + l16)*64 + (((kk*4+lkb)) ^ sw)*8];
#pragma unroll
      for (int j = 0; j < FN; j++)
        bfh[kk][j] = *(const bf16x8*)&bufB[(wc*(BN/2) + j*16 + l16)*64 + (((kk*4+lkb)) ^ sw)*8];
    }
    __builtin_amdgcn_s_barrier();
    if (T + 2 < NK)
      pg_stage<ACW,BCW>(A, W, lds[T & 1], lds[T & 1] + BM*64, m0, n0, Nn, Kk, T + 2, w, lane, lr, sx);
    __builtin_amdgcn_s_setprio(1);
#pragma unroll
    for (int kk = 0; kk < 2; kk++)
#pragma unroll
      for (int i = 0; i < FM; i++)
#pragma unroll
        for (int j = 0; j < FN; j++)
          acc[i][j] = MFMA16(af[kk][i], bfh[kk][j], acc[i][j], 0, 0, 0);
    __builtin_amdgcn_s_setprio(0);
  }

#pragma unroll
  for (int i = 0; i < FM; i++) {
    int gr0 = m0 + wr*(BM/2) + i*16 + lkb*4;
#pragma unroll
    for (int j = 0; j < FN; j++) {
      int gc = n0 + wc*(BN/2) + j*16 + l16;
      if (gc < Nn) {
#pragma unroll
        for (int r = 0; r < 4; r++) {
          size_t idx = (size_t)(gr0 + r) * Nn + gc;
          float val = acc[i][j][r];
          if (EPI == 0) C[idx] = val;
          else C[idx] += val;
        }
      }
    }
  }
}

// ======================================================================
// PIPELINED fused FFN w1/w2 GEMM (dual-B), 128x64, L=8.
// ======================================================================
__device__ __forceinline__ void pf_stage(const us* __restrict__ A,
                                         const us* __restrict__ W1,
                                         const us* __restrict__ W2,
                                         us* buf, int m0, int n0, int Nn, int Kk,
                                         int tile, int w, int lane, int lr, int sx) {
#pragma unroll
  for (int i = 0; i < 4; i++) {
    int chunk = w * 4 + i;
    G2L16(A + (size_t)(m0 + chunk*8 + lr) * Kk + tile*64 + sx, buf + chunk*512 + lane*8);
  }
#pragma unroll
  for (int i = 0; i < 2; i++) {
    int chunk = w * 2 + i;
    int wrow = n0 + chunk*8 + lr;
    if (wrow >= Nn) wrow = Nn - 1;
    G2L16(W1 + (size_t)wrow * Kk + tile*64 + sx, buf + 8192 + chunk*512 + lane*8);
    G2L16(W2 + (size_t)wrow * Kk + tile*64 + sx, buf + 12288 + chunk*512 + lane*8);
  }
}

__global__ __launch_bounds__(256) void k_pffn12(const us* __restrict__ A,
                                                const us* __restrict__ W1,
                                                const us* __restrict__ W2,
                                                us* __restrict__ Cb,
                                                int Nn, int Kk) {
  __shared__ __attribute__((aligned(16))) us lds[2][16384];
  int t = threadIdx.x, lane = t & 63, w = t >> 6;
  int l16 = lane & 15, lkb = lane >> 4, lr = lane >> 3;
  int sx = ((lane & 7) ^ lr) * 8;
  int sw = l16 & 7;
  int gx = gridDim.x, nwg = gx * gridDim.y;
  int nf = xcd_remap(blockIdx.y * gx + blockIdx.x, nwg);
  int m0 = (nf % gx) * 128, n0 = (nf / gx) * 64;
  int wr = w >> 1, wc = w & 1;
  int NK = Kk >> 6;

  pf_stage(A, W1, W2, lds[0], m0, n0, Nn, Kk, 0, w, lane, lr, sx);
  pf_stage(A, W1, W2, lds[1], m0, n0, Nn, Kk, 1, w, lane, lr, sx);

  fv4 acc1[4][2] = {}, acc2[4][2] = {};
  for (int T = 0; T < NK; T++) {
    if (T == NK - 1) waitcnt_vm<0>(); else waitcnt_vm<8>();
    __builtin_amdgcn_s_barrier();
    const us* buf = lds[T & 1];
    bf16x8 af[2][4], b1f[2][2], b2f[2][2];
#pragma unroll
    for (int kk = 0; kk < 2; kk++) {
#pragma unroll
      for (int i = 0; i < 4; i++)
        af[kk][i] = *(const bf16x8*)&buf[(wr*64 + i*16 + l16)*64 + ((kk*4+lkb) ^ sw)*8];
#pragma unroll
      for (int j = 0; j < 2; j++) {
        b1f[kk][j] = *(const bf16x8*)&buf[8192  + (wc*32 + j*16 + l16)*64 + ((kk*4+lkb) ^ sw)*8];
        b2f[kk][j] = *(const bf16x8*)&buf[12288 + (wc*32 + j*16 + l16)*64 + ((kk*4+lkb) ^ sw)*8];
      }
    }
    __builtin_amdgcn_s_barrier();
    if (T + 2 < NK)
      pf_stage(A, W1, W2, lds[T & 1], m0, n0, Nn, Kk, T + 2, w, lane, lr, sx);
    __builtin_amdgcn_s_setprio(1);
#pragma unroll
    for (int kk = 0; kk < 2; kk++)
#pragma unroll
      for (int i = 0; i < 4; i++)
#pragma unroll
        for (int j = 0; j < 2; j++) {
          acc1[i][j] = MFMA16(af[kk][i], b1f[kk][j], acc1[i][j], 0, 0, 0);
          acc2[i][j] = MFMA16(af[kk][i], b2f[kk][j], acc2[i][j], 0, 0, 0);
        }
    __builtin_amdgcn_s_setprio(0);
  }

#pragma unroll
  for (int i = 0; i < 4; i++) {
    int gr0 = m0 + wr*64 + i*16 + lkb*4;
#pragma unroll
    for (int j = 0; j < 2; j++) {
      int gc = n0 + wc*32 + j*16 + l16;
      if (gc < Nn) {
#pragma unroll
        for (int r = 0; r < 4; r++) {
          float v1 = acc1[i][j][r], v2 = acc2[i][j][r];
          float sv = v1 / (1.f + expf(-v1));
          Cb[(size_t)(gr0 + r) * FFP + gc] = f2bf(sv * v2);
        }
      }
    }
  }
}

// ======================================================================
// PIPELINED qkv GEMM + head-split + qk-rmsnorm + rope epilogue.
// ======================================================================
__global__ __launch_bounds__(256) void k_pqkv(const us* __restrict__ A,
                                              const us* __restrict__ W,
                                              const float* __restrict__ qnw,
                                              const float* __restrict__ knw,
                                              const float* __restrict__ cosT,
                                              const float* __restrict__ sinT,
                                              us* __restrict__ qb,
                                              us* __restrict__ kb,
                                              us* __restrict__ vb) {
  const int Kk = D, Nn = 3 * D;
  __shared__ __attribute__((aligned(16))) us lds[2][16384];
  int t = threadIdx.x, lane = t & 63, w = t >> 6;
  int l16 = lane & 15, lkb = lane >> 4, lr = lane >> 3;
  int sx = ((lane & 7) ^ lr) * 8;
  int sw = l16 & 7;
  int gx = gridDim.x, nwg = gx * gridDim.y;
  int nf = xcd_remap(blockIdx.y * gx + blockIdx.x, nwg);
  int m0 = (nf % gx) * 128, n0 = (nf / gx) * 128;
  int wr = w >> 1, wc = w & 1;
  int NK = Kk >> 6;

  pg_stage<4,4>(A, W, lds[0], lds[0] + 8192, m0, n0, Nn, Kk, 0, w, lane, lr, sx);
  pg_stage<4,4>(A, W, lds[1], lds[1] + 8192, m0, n0, Nn, Kk, 1, w, lane, lr, sx);

  fv4 acc[4][4] = {};
  for (int T = 0; T < NK; T++) {
    if (T == NK - 1) waitcnt_vm<0>(); else waitcnt_vm<8>();
    __builtin_amdgcn_s_barrier();
    const us* bufA = lds[T & 1];
    const us* bufB = bufA + 8192;
    bf16x8 af[2][4], bfh[2][4];
#pragma unroll
    for (int kk = 0; kk < 2; kk++) {
#pragma unroll
      for (int i = 0; i < 4; i++) {
        af[kk][i]  = *(const bf16x8*)&bufA[(wr*64 + i*16 + l16)*64 + ((kk*4+lkb) ^ sw)*8];
        bfh[kk][i] = *(const bf16x8*)&bufB[(wc*64 + i*16 + l16)*64 + ((kk*4+lkb) ^ sw)*8];
      }
    }
    __builtin_amdgcn_s_barrier();
    if (T + 2 < NK)
      pg_stage<4,4>(A, W, lds[T & 1], lds[T & 1] + 8192, m0, n0, Nn, Kk, T + 2, w, lane, lr, sx);
    __builtin_amdgcn_s_setprio(1);
#pragma unroll
    for (int kk = 0; kk < 2; kk++)
#pragma unroll
      for (int i = 0; i < 4; i++)
#pragma unroll
        for (int j = 0; j < 4; j++)
          acc[i][j] = MFMA16(af[kk][i], bfh[kk][j], acc[i][j], 0, 0, 0);
    __builtin_amdgcn_s_setprio(0);
  }

  // ---- fused epilogue ----
  int part = n0 >> 10;
  int hd = ((n0 & 1023) + wc * 64) >> 6;
  us* dst = (part == 0) ? qb : ((part == 1) ? kb : vb);
  if (part == 2) {
#pragma unroll
    for (int i = 0; i < 4; i++)
#pragma unroll
      for (int r = 0; r < 4; r++) {
        int m = m0 + wr*64 + i*16 + lkb*4 + r;
        int b = m >> 10, s = m & 1023;
        us* drow = dst + (((size_t)(b*H + hd)) * S + s) * 64;
#pragma unroll
        for (int j = 0; j < 4; j++) drow[j*16 + l16] = f2bf(acc[i][j][r]);
      }
  } else {
    const float* nw = (part == 0) ? qnw : knw;
    float w0 = nw[l16], w1 = nw[16 + l16], w2 = nw[32 + l16], w3 = nw[48 + l16];
#pragma unroll
    for (int i = 0; i < 4; i++)
#pragma unroll
      for (int r = 0; r < 4; r++) {
        int m = m0 + wr*64 + i*16 + lkb*4 + r;
        int b = m >> 10, s = m & 1023;
        float a0 = acc[i][0][r], a1 = acc[i][1][r], a2 = acc[i][2][r], a3 = acc[i][3][r];
        float s2 = a0*a0 + a1*a1 + a2*a2 + a3*a3;
        s2 += __shfl_xor(s2, 1); s2 += __shfl_xor(s2, 2);
        s2 += __shfl_xor(s2, 4); s2 += __shfl_xor(s2, 8);
        float rs = rsqrtf(s2 * (1.0f / (float)DH) + 1e-6f);
        float v0 = a0 * rs * w0, v1 = a1 * rs * w1, v2 = a2 * rs * w2, v3 = a3 * rs * w3;
        float c0 = cosT[s*32 + l16],      sn0 = sinT[s*32 + l16];
        float c1 = cosT[s*32 + 16 + l16], sn1 = sinT[s*32 + 16 + l16];
        us* drow = dst + (((size_t)(b*H + hd)) * S + s) * 64;
        drow[l16]      = f2bf(v0 * c0 - v2 * sn0);
        drow[16 + l16] = f2bf(v1 * c1 - v3 * sn1);
        drow[32 + l16] = f2bf(v2 * c0 + v0 * sn0);
        drow[48 + l16] = f2bf(v3 * c1 + v1 * sn1);
      }
  }
}

// ======================================================================
// 256x256 8-wave deep-pipelined bf16 GEMM — lm_head (unchanged).
// ======================================================================
struct G8 { const us* A; const us* W; int K; int m0; int n0; };

__device__ __forceinline__ void g8_issue(const G8& g, us* lds8, int q, int t) {
  int tile = q >> 2, h = q & 3;
  us* buf = lds8 + (size_t)(tile & 1) * 32768;
  const us* Gp = (h < 2) ? g.A : g.W;
  int rbase = ((h < 2) ? g.m0 : g.n0) + (h & 1) * 128;
  us* part = buf + (h >> 1) * 16384 + (h & 1) * 8192;
  int r8 = t >> 3;
  int sl = (((t & 7) ^ (r8 & 7)) * 8);
#pragma unroll
  for (int c = 0; c < 2; c++) {
    const us* src = Gp + (size_t)(rbase + c * 64 + r8) * g.K + tile * 64 + sl;
    us* dst = part + c * 4096 + t * 8;
    G2L16(src, dst);
  }
}

__global__ __launch_bounds__(512, 2) void k_gemm8(const us* __restrict__ A,
                                                  const us* __restrict__ W,
                                                  float* __restrict__ C,
                                                  int Nn, int Kk) {
  __shared__ __attribute__((aligned(16))) us lds8[65536];
  int t = threadIdx.x, lane = t & 63, w = t >> 6;
  int wm = w >> 2, wn = w & 3;
  int l16 = lane & 15, lkb = lane >> 4;
  int gx = gridDim.x, nwg = gx * gridDim.y;
  int nf = xcd_remap(blockIdx.y * gx + blockIdx.x, nwg);
  int m0 = (nf % gx) * 256, n0 = (nf / gx) * 256;
  G8 g{A, W, Kk, m0, n0};
  int NK = Kk >> 6, QMAX = NK * 4;

  int q = 0;
  for (; q < 7 && q < QMAX; ++q) g8_issue(g, lds8, q, t);

  fv4 acc[8][4] = {};
  int arow = wm * 128 + l16;
  int brow = wn * 64 + l16;
  int sw = l16 & 7;

  for (int T = 0; T < NK; ++T) {
    if (q < QMAX) { g8_issue(g, lds8, q, t); q++; }
    if (T == NK - 1) asm volatile("s_waitcnt vmcnt(0)" ::: "memory");
    else             asm volatile("s_waitcnt vmcnt(8)" ::: "memory");
    __builtin_amdgcn_s_barrier();
    const us* buf = lds8 + (size_t)(T & 1) * 32768;
    bf16x8 a0[8], a1[8], b0[4], b1[4];
#pragma unroll
    for (int i = 0; i < 8; i++) {
      a0[i] = *(const bf16x8*)&buf[(arow + i*16)*64 + ((lkb     ) ^ sw)*8];
      a1[i] = *(const bf16x8*)&buf[(arow + i*16)*64 + ((lkb +  4) ^ sw)*8];
    }
#pragma unroll
    for (int j = 0; j < 4; j++) {
      b0[j] = *(const bf16x8*)&buf[16384 + (brow + j*16)*64 + ((lkb    ) ^ sw)*8];
      b1[j] = *(const bf16x8*)&buf[16384 + (brow + j*16)*64 + ((lkb + 4) ^ sw)*8];
    }
    __builtin_amdgcn_s_barrier();
    __builtin_amdgcn_s_setprio(1);
#pragma unroll
    for (int i = 0; i < 8; i++)
#pragma unroll
      for (int j = 0; j < 4; j++)
        acc[i][j] = MFMA16(a0[i], b0[j], acc[i][j], 0, 0, 0);
    __builtin_amdgcn_s_setprio(0);
    if (q < QMAX) { g8_issue(g, lds8, q, t); q++; }
    if (q < QMAX) { g8_issue(g, lds8, q, t); q++; }
    if (q < QMAX) { g8_issue(g, lds8, q, t); q++; }
    __builtin_amdgcn_s_setprio(1);
#pragma unroll
    for (int i = 0; i < 8; i++)
#pragma unroll
      for (int j = 0; j < 4; j++)
        acc[i][j] = MFMA16(a1[i], b1[j], acc[i][j], 0, 0, 0);
    __builtin_amdgcn_s_setprio(0);
  }

#pragma unroll
  for (int i = 0; i < 8; i++) {
    int gr0 = m0 + wm*128 + i*16 + lkb*4;
#pragma unroll
    for (int j = 0; j < 4; j++) {
      int gc = n0 + wn*64 + j*16 + l16;
#pragma unroll
      for (int r = 0; r < 4; r++)
        C[(size_t)(gr0 + r) * Nn + gc] = acc[i][j][r];
    }
  }
}

// ======================================================================
// 64x64 bf16 transpose: (bh, s, dh) -> (bh, dh, s); grid.z selects k or v
// ======================================================================
__global__ __launch_bounds__(256) void k_tr2(const us* __restrict__ ksrc,
                                             const us* __restrict__ vsrc,
                                             us* __restrict__ kdst,
                                             us* __restrict__ vdst) {
  __shared__ __attribute__((aligned(16))) us tile[64*72];
  int st = blockIdx.x, bh = blockIdx.y, t = threadIdx.x;
  const us* src = blockIdx.z ? vsrc : ksrc;
  us* dst = blockIdx.z ? vdst : kdst;
  const us* sp = src + ((size_t)bh * S + st*64) * 64;
#pragma unroll
  for (int p = 0; p < 2; p++) {
    int idx = t + p*256;
    int r = idx >> 3, c = (idx & 7)*8;
    *(bf16x8*)&tile[r*72 + c] = *(const bf16x8*)&sp[(size_t)idx*8];
  }
  __syncthreads();
  int d = t >> 2;
#pragma unroll
  for (int cc = 0; cc < 16; cc += 8) {
    int s0 = (t & 3)*16 + cc;
    bf16x8 vv;
#pragma unroll
    for (int j2 = 0; j2 < 8; j2++) vv[j2] = (short)tile[(s0+j2)*72 + d];
    *(bf16x8*)&dst[((size_t)bh*64 + d)*S + st*64 + s0] = vv;
  }
}

// ======================================================================
// FUSED omega-memory + flash attention — pipelined staging + IN-BLOCK
// gk prefix scan (replaces k_cumsum; block already holds full gk row).
// ======================================================================
#define SM_OFF 24.0f

__device__ __forceinline__ void m_stage(const us* __restrict__ src, int rstride,
                                        us* buf, int w, int lane, int lr, int sx8) {
#pragma unroll
  for (int i = 0; i < 2; i++) {
    int rbase = i * 32 + w * 8;
    G2L16(src + (size_t)(rbase + lr) * rstride + sx8, buf + rbase * 64 + lane * 8);
  }
}

__global__ __launch_bounds__(256) void k_matt(const us* __restrict__ qb,
                                              const us* __restrict__ kb,
                                              const us* __restrict__ kbT,
                                              const us* __restrict__ vbT,
                                              const us* __restrict__ MpB,
                                              const float* __restrict__ gk,
                                              const float* __restrict__ mg, int layer,
                                              us* __restrict__ ob) {
  int nf = xcd_remap(blockIdx.y * 8 + blockIdx.x, 256);
  int xx = nf & 7, bh = nf >> 3;
  int b = bh >> 4, hh = bh & 15;
  int t = threadIdx.x, lane = t & 63, w = t >> 6;
  int l16 = lane & 15, lg = lane >> 4, lr = lane >> 3;
  int sx8 = ((lane & 7) ^ lr) * 8;
  int sw = l16 & 7;

  __shared__ __attribute__((aligned(16))) us Qs[64*72];
  __shared__ __attribute__((aligned(16))) us Ms[64*72];
  __shared__ __attribute__((aligned(16))) us Ps[64*72];
  __shared__ __attribute__((aligned(16))) us KT[2][2][64*64];
  __shared__ float gkL[S], nrmL[S];
  __shared__ float wsum2[4];

  float gate = 1.f / (1.f + expf(-mg[layer]));
  const us* kbB = kb + (size_t)bh * S * 64;
  const us* ktB = kbT + (size_t)bh * 64 * S;
  const us* vtB = vbT + (size_t)bh * 64 * S;

  // ---- once per block: Mp, gk row, and in-block prefix scan ----
  {
    const us* mp = MpB + (size_t)hh * 4096;
#pragma unroll
    for (int p = 0; p < 2; p++) {
      int idx = t + p*256;
      int r = idx >> 3, c = (idx & 7) * 8;
      *(bf16x8*)&Ms[r*72 + c] = *(const bf16x8*)&mp[(size_t)idx*8];
    }
#pragma unroll
    for (int p = 0; p < 4; p++) gkL[t + p*256] = gk[b*S + t + p*256];
  }
  __syncthreads();
  {
    float v0 = gkL[4*t], v1 = gkL[4*t+1], v2 = gkL[4*t+2], v3 = gkL[4*t+3];
    float r0 = v0, r1 = r0 + v1, r2 = r1 + v2, r3 = r2 + v3;
    float s = r3;
#pragma unroll
    for (int off = 1; off < 64; off <<= 1) {
      float y = __shfl_up(s, off, 64);
      if (lane >= off) s += y;
    }
    if (lane == 63) wsum2[w] = s;
    __syncthreads();
    float wexcl = 0.f;
    if (w == 1) wexcl = wsum2[0];
    else if (w == 2) wexcl = wsum2[0] + wsum2[1];
    else if (w == 3) wexcl = wsum2[0] + wsum2[1] + wsum2[2];
    float base = wexcl + (s - r3);
    nrmL[4*t]   = (float)NP + base + r0;
    nrmL[4*t+1] = (float)NP + base + r1;
    nrmL[4*t+2] = (float)NP + base + r2;
    nrmL[4*t+3] = (float)NP + base + r3;
  }

  for (int sel = 0; sel < 2; sel++) {
    int qt = sel ? (15 - xx) : xx;
    __syncthreads();
    {
      const us* src = qb + ((size_t)bh * S + qt*64) * 64;
#pragma unroll
      for (int p = 0; p < 2; p++) {
        int idx = t + p*256;
        int r = idx >> 3, c = (idx & 7) * 8;
        *(bf16x8*)&Qs[r*72 + c] = *(const bf16x8*)&src[(size_t)idx*8];
      }
    }
    __syncthreads();

    bf16x8 aq0 = *(const bf16x8*)&Qs[(16*w + l16)*72 + lg*8];
    bf16x8 aq1 = *(const bf16x8*)&Qs[(16*w + l16)*72 + 32 + lg*8];

    fv4 am[4];
#pragma unroll
    for (int j = 0; j < 4; j++) {
      bf16x8 b0 = *(const bf16x8*)&Ms[(16*j + l16)*72 + lg*8];
      bf16x8 b1 = *(const bf16x8*)&Ms[(16*j + l16)*72 + 32 + lg*8];
      fv4 z = {};
      z = MFMA16(aq0, b0, z, 0, 0, 0);
      z = MFMA16(aq1, b1, z, 0, 0, 0);
      am[j] = z;
    }

    // ======== phase 1: omega memory (pipelined K + K^T) ========
    m_stage(kbB,            64, KT[0][0], w, lane, lr, sx8);
    m_stage(ktB,            S,  KT[0][1], w, lane, lr, sx8);
    m_stage(kbB + 4096,     64, KT[1][0], w, lane, lr, sx8);
    m_stage(ktB + 64,       S,  KT[1][1], w, lane, lr, sx8);
    for (int kt = 0; kt <= qt; kt++) {
      int ks = kt * 64;
      if (kt == qt) waitcnt_vm<0>(); else waitcnt_vm<4>();
      __builtin_amdgcn_s_barrier();
      const us* bK = KT[kt & 1][0];
      const us* bT = KT[kt & 1][1];
      bf16x8 kf0[4], kf1[4], tf0[4], tf1[4];
      float gv[4];
#pragma unroll
      for (int j = 0; j < 4; j++) {
        int row = 16*j + l16;
        kf0[j] = *(const bf16x8*)&bK[row*64 + ((lg    ) ^ sw)*8];
        kf1[j] = *(const bf16x8*)&bK[row*64 + ((lg + 4) ^ sw)*8];
        tf0[j] = *(const bf16x8*)&bT[row*64 + ((lg    ) ^ sw)*8];
        tf1[j] = *(const bf16x8*)&bT[row*64 + ((lg + 4) ^ sw)*8];
        gv[j] = gkL[ks + row];
      }
      __builtin_amdgcn_s_barrier();
      if (kt + 2 <= qt) {
        m_stage(kbB + (size_t)(kt+2)*4096, 64, KT[kt & 1][0], w, lane, lr, sx8);
        m_stage(ktB + (kt+2)*64,           S,  KT[kt & 1][1], w, lane, lr, sx8);
      }
      fv4 sc[4];
      __builtin_amdgcn_s_setprio(1);
#pragma unroll
      for (int j = 0; j < 4; j++) {
        fv4 z = {};
        z = MFMA16(aq0, kf0[j], z, 0, 0, 0);
        z = MFMA16(aq1, kf1[j], z, 0, 0, 0);
        sc[j] = z;
      }
      __builtin_amdgcn_s_setprio(0);
      if (kt < qt) {
#pragma unroll
        for (int j = 0; j < 4; j++)
#pragma unroll
          for (int r = 0; r < 4; r++)
            Ps[(16*w + lg*4 + r)*72 + 16*j + l16] = f2bf(sc[j][r] * gv[j]);
      } else {
#pragma unroll
        for (int j = 0; j < 4; j++) {
          int kj = 16*j + l16;
#pragma unroll
          for (int r = 0; r < 4; r++) {
            int qi = 16*w + lg*4 + r;
            Ps[qi*72 + kj] = (kj > qi) ? (us)0 : f2bf(sc[j][r] * gv[j]);
          }
        }
      }
      bf16x8 ap0 = *(const bf16x8*)&Ps[(16*w + l16)*72 + lg*8];
      bf16x8 ap1 = *(const bf16x8*)&Ps[(16*w + l16)*72 + 32 + lg*8];
      __builtin_amdgcn_s_setprio(1);
#pragma unroll
      for (int j = 0; j < 4; j++) {
        am[j] = MFMA16(ap0, tf0[j], am[j], 0, 0, 0);
        am[j] = MFMA16(ap1, tf1[j], am[j], 0, 0, 0);
      }
      __builtin_amdgcn_s_setprio(0);
    }

    // q' update: Qs rows wave-private -> no barriers
#pragma unroll
    for (int j = 0; j < 4; j++)
#pragma unroll
      for (int r = 0; r < 4; r++) {
        int qi = 16*w + lg*4 + r, dj = 16*j + l16;
        float qold = bf2f(Qs[qi*72 + dj]);
        float qn = (1.f - gate) * qold + gate * (am[j][r] / nrmL[qt*64 + qi]);
        Qs[qi*72 + dj] = f2bf(qn);
      }
    aq0 = *(const bf16x8*)&Qs[(16*w + l16)*72 + lg*8];
    aq1 = *(const bf16x8*)&Qs[(16*w + l16)*72 + 32 + lg*8];

    // ======== phase 2: flash attention (pipelined K + V^T) ========
    float lsum[4] = {};
    fv4 ao[4] = {};
    m_stage(kbB,            64, KT[0][0], w, lane, lr, sx8);
    m_stage(vtB,            S,  KT[0][1], w, lane, lr, sx8);
    m_stage(kbB + 4096,     64, KT[1][0], w, lane, lr, sx8);
    m_stage(vtB + 64,       S,  KT[1][1], w, lane, lr, sx8);
    for (int kt = 0; kt <= qt; kt++) {
      if (kt == qt) waitcnt_vm<0>(); else waitcnt_vm<4>();
      __builtin_amdgcn_s_barrier();
      const us* bK = KT[kt & 1][0];
      const us* bV = KT[kt & 1][1];
      bf16x8 kf0[4], kf1[4], vf0[4], vf1[4];
#pragma unroll
      for (int j = 0; j < 4; j++) {
        int row = 16*j + l16;
        kf0[j] = *(const bf16x8*)&bK[row*64 + ((lg    ) ^ sw)*8];
        kf1[j] = *(const bf16x8*)&bK[row*64 + ((lg + 4) ^ sw)*8];
        vf0[j] = *(const bf16x8*)&bV[row*64 + ((lg    ) ^ sw)*8];
        vf1[j] = *(const bf16x8*)&bV[row*64 + ((lg + 4) ^ sw)*8];
      }
      __builtin_amdgcn_s_barrier();
      if (kt + 2 <= qt) {
        m_stage(kbB + (size_t)(kt+2)*4096, 64, KT[kt & 1][0], w, lane, lr, sx8);
        m_stage(vtB + (kt+2)*64,           S,  KT[kt & 1][1], w, lane, lr, sx8);
      }
      fv4 sc[4];
      __builtin_amdgcn_s_setprio(1);
#pragma unroll
      for (int j = 0; j < 4; j++) {
        fv4 z = {};
        z = MFMA16(aq0, kf0[j], z, 0, 0, 0);
        z = MFMA16(aq1, kf1[j], z, 0, 0, 0);
        sc[j] = z;
      }
      __builtin_amdgcn_s_setprio(0);
      if (kt < qt) {
#pragma unroll
        for (int j = 0; j < 4; j++)
#pragma unroll
          for (int r = 0; r < 4; r++) {
            float p = __expf(fmaf(sc[j][r], 0.125f, -SM_OFF));
            lsum[r] += p;
            Ps[(16*w + lg*4 + r)*72 + 16*j + l16] = f2bf(p);
          }
      } else {
#pragma unroll
        for (int j = 0; j < 4; j++) {
          int kj = 16*j + l16;
#pragma unroll
          for (int r = 0; r < 4; r++) {
            int qi = 16*w + lg*4 + r;
            float p = (kj > qi) ? 0.f : __expf(fmaf(sc[j][r], 0.125f, -SM_OFF));
            lsum[r] += p;
            Ps[qi*72 + kj] = f2bf(p);
          }
        }
      }
      bf16x8 ap0 = *(const bf16x8*)&Ps[(16*w + l16)*72 + lg*8];
      bf16x8 ap1 = *(const bf16x8*)&Ps[(16*w + l16)*72 + 32 + lg*8];
      __builtin_amdgcn_s_setprio(1);
#pragma unroll
      for (int j = 0; j < 4; j++) {
        ao[j] = MFMA16(ap0, vf0[j], ao[j], 0, 0, 0);
        ao[j] = MFMA16(ap1, vf1[j], ao[j], 0, 0, 0);
      }
      __builtin_amdgcn_s_setprio(0);
    }

#pragma unroll
    for (int r = 0; r < 4; r++) {
      float l = lsum[r];
      l += __shfl_xor(l, 1);
      l += __shfl_xor(l, 2);
      l += __shfl_xor(l, 4);
      l += __shfl_xor(l, 8);
      lsum[r] = l;
    }
#pragma unroll
    for (int j = 0; j < 4; j++)
#pragma unroll
      for (int r = 0; r < 4; r++) {
        int qi = 16*w + lg*4 + r;
        ob[((size_t)b*S + qt*64 + qi) * D + hh*64 + 16*j + l16] = f2bf(ao[j][r] / lsum[r]);
      }
  }
}

// ======================================================================
// launcher
// ======================================================================
extern "C" void kernel_launch(void* const* d_in, const int* in_sizes, int n_in,
                              void* d_out, int out_size, void* d_ws, size_t ws_size,
                              hipStream_t stream) {
  const int*   ids      = (const int*)d_in[0];
  const float* tok_emb  = (const float*)d_in[1];
  const float* w_init   = (const float*)d_in[2];
  const float* persist  = (const float*)d_in[3];
  const float* norm1_w  = (const float*)d_in[4];
  const float* norm2_w  = (const float*)d_in[5];
  const float* norm_f_w = (const float*)d_in[6];
  const float* qkv_w    = (const float*)d_in[7];
  const float* q_norm_w = (const float*)d_in[8];
  const float* k_norm_w = (const float*)d_in[9];
  const float* gamma_w1 = (const float*)d_in[10];
  const float* gamma_w2 = (const float*)d_in[11];
  const float* mem_gate = (const float*)d_in[12];
  const float* w_o      = (const float*)d_in[13];
  const float* ffn_w1   = (const float*)d_in[14];
  const float* ffn_w2   = (const float*)d_in[15];
  const float* ffn_w3   = (const float*)d_in[16];
  float* out = (float*)d_out;

  // ---- workspace layout ----
  float* ws   = (float*)d_ws;
  float* x    = ws;                          // 2097152 f32
  us*    hbf  = (us*)(x + 2097152);          // 2097152 us
  float* gk   = x + 2097152 + 1048576;
  float* nrm  = gk + 2048;                   // dead slot
  float* cosT = nrm + 2048;
  float* sinT = cosT + 32768;
  us*    MpBH = (us*)(sinT + 32768);         // H*DH*DH us
  float* h    = sinT + 32768 + 65536;        // dead slot (temb alias base)
  float* qkv  = h + 2097152;                 // dead slot
  us*    obf  = (us*)(qkv + 6291456);        // 2097152 us
  us*    qb   = obf + 2097152;
  us*    kb   = qb + 2097152;
  us*    vb   = kb + 2097152;
  us*    kbT  = vb + 2097152;
  us*    vbT  = kbT + 2097152;
  us*    f1bf = vbT + 2097152;               // M*FFP = 5636096 us
  us*    wq   = f1bf + (size_t)M*FFP;        // 3145728
  us*    wo   = wq + 3145728;                // 1048576
  us*    w1c  = wo + 1048576;                // 2795520
  us*    w2c  = w1c + 2795520;               // 2795520
  us*    w3c  = w2c + 2795520;               // 2818048
  us*    temb = (us*)h;                      // aliases dead h..f1bf span

  k_embed<<<M, 256, 0, stream>>>(ids, tok_emb, w_init, x);
  k_rope_tables<<<(S*32 + 255)/256, 256, 0, stream>>>(cosT, sinT);
  k_mp<<<H, 256, 0, stream>>>(persist, MpBH);

  for (int l = 0; l < NL; l++) {
    k_cvtw<<<2048, 256, 0, stream>>>(qkv_w + (size_t)l*3*D*D, w_o + (size_t)l*D*D,
                                     ffn_w1 + (size_t)l*FF*D, ffn_w2 + (size_t)l*FF*D,
                                     ffn_w3 + (size_t)l*D*FF,
                                     wq, wo, w1c, w2c, w3c);
    k_rmsg<<<M, 256, 0, stream>>>(x, norm1_w + (size_t)l * D,
                                  gamma_w1 + (size_t)l*GH*D, gamma_w2 + (size_t)l*GH,
                                  hbf, gk);
    k_pqkv<<<dim3(16, 24), 256, 0, stream>>>(hbf, wq,
                                             q_norm_w + (size_t)l*DH, k_norm_w + (size_t)l*DH,
                                             cosT, sinT, qb, kb, vb);
    k_tr2<<<dim3(S/64, B*H, 2), 256, 0, stream>>>(kb, vb, kbT, vbT);
    k_matt<<<dim3(8, B*H), 256, 0, stream>>>(qb, kb, kbT, vbT, MpBH, gk, mem_gate, l, obf);
    k_pgemm<2,128,64><<<dim3(M/128, D/64), 256, 0, stream>>>(obf, wo, x, D, D);
    k_rms<<<M, 256, 0, stream>>>(x, norm2_w + (size_t)l * D, hbf);
    k_pffn12<<<dim3(M/128, (FF+63)/64), 256, 0, stream>>>(hbf, w1c, w2c, f1bf, FF, D);
    k_pgemm<2,128,64><<<dim3(M/128, D/64), 256, 0, stream>>>(f1bf, w3c, x, D, FFP);
  }

  k_rms<<<M, 256, 0, stream>>>(x, norm_f_w, hbf);
  k_cvt<<<2048, 256, 0, stream>>>(tok_emb, temb, V*D);
  k_gemm8<<<dim3(8, V/256), 512, 0, stream>>>(hbf, temb, out, V, D);
}

// Round 15
// 1418.742 us; speedup vs baseline: 1.0245x; 1.0245x over previous
//
#include <hip/hip_runtime.h>
#include <hip/hip_bf16.h>
#include <math.h>

// ---------------- problem constants ----------------
#define B 2
#define S 1024
#define D 1024
#define H 16
#define DH 64
#define NL 6
#define GH 64
#define NP 16
#define V 32000
#define FF 2730
#define FFP 2752   // FF padded to multiple of 64
#define M (B*S)    // 2048 rows

typedef float fv4 __attribute__((ext_vector_type(4)));
typedef short bf16x8 __attribute__((ext_vector_type(8)));       // 8 bf16 = 4 VGPRs
typedef unsigned short us4 __attribute__((ext_vector_type(4))); // 4 bf16 = 8 bytes
typedef unsigned short us;

#define MFMA16 __builtin_amdgcn_mfma_f32_16x16x32_bf16
#define G2L16(g, l) __builtin_amdgcn_global_load_lds( \
    (const __attribute__((address_space(1))) void*)(g), \
    (__attribute__((address_space(3))) void*)(l), 16, 0, 0)

__device__ __forceinline__ us f2bf(float f) {
  union { float f; unsigned u; } v; v.f = f;
  unsigned r = v.u + 0x7FFFu + ((v.u >> 16) & 1u);   // RNE
  return (us)(r >> 16);
}
__device__ __forceinline__ float bf2f(us h) {
  union { unsigned u; float f; } v; v.u = ((unsigned)h) << 16;
  return v.f;
}

template<int N> __device__ __forceinline__ void waitcnt_vm() {
  if constexpr (N == 0)      asm volatile("s_waitcnt vmcnt(0)" ::: "memory");
  else if constexpr (N == 4) asm volatile("s_waitcnt vmcnt(4)" ::: "memory");
  else if constexpr (N == 8) asm volatile("s_waitcnt vmcnt(8)" ::: "memory");
  else if constexpr (N == 6) asm volatile("s_waitcnt vmcnt(6)" ::: "memory");
}

// m204 bijective XCD swizzle
__device__ __forceinline__ int xcd_remap(int flat, int nwg) {
  int q = nwg >> 3, r = nwg & 7;
  int xcd = flat & 7, idx = flat >> 3;
  return (xcd < r) ? (xcd * (q + 1) + idx) : (r * (q + 1) + (xcd - r) * q + idx);
}

// ======================================================================
// embed
// ======================================================================
__global__ __launch_bounds__(256) void k_embed(const int* __restrict__ ids,
                                               const float* __restrict__ emb,
                                               const float* __restrict__ winit,
                                               float* __restrict__ x) {
  int m = blockIdx.x, t = threadIdx.x;
  int id = ids[m];
  fv4 a = *(const fv4*)(emb + (size_t)id * D + 4*t);
  fv4 w = *(const fv4*)(winit + 4*t);
  *(fv4*)(x + (size_t)m * D + 4*t) = a + w;
}

// ======================================================================
// rope tables
// ======================================================================
__global__ void k_rope_tables(float* __restrict__ cosT, float* __restrict__ sinT) {
  int idx = blockIdx.x * blockDim.x + threadIdx.x;
  if (idx >= S * 32) return;
  int s = idx >> 5, f = idx & 31;
  float inv = powf(10000.0f, -2.0f * (float)f / (float)DH);
  float ang = (float)s * inv;
  cosT[idx] = cosf(ang);
  sinT[idx] = sinf(ang);
}

// ======================================================================
// Mp[h][d][e] -> bf16
// ======================================================================
__global__ __launch_bounds__(256) void k_mp(const float* __restrict__ pers,
                                            us* __restrict__ Mp) {
  int h = blockIdx.x, t = threadIdx.x;
  __shared__ float p[NP][DH];
  for (int i = t; i < NP * DH; i += 256) {
    int n = i / DH, dh = i % DH;
    p[n][dh] = pers[(size_t)n * D + h * DH + dh];
  }
  __syncthreads();
  for (int i = t; i < DH * DH; i += 256) {
    int d = i / DH, e = i % DH;
    float s = 0.f;
#pragma unroll
    for (int n = 0; n < NP; n++) s += p[n][d] * p[n][e];
    Mp[(size_t)h * DH * DH + i] = f2bf(s);
  }
}

// ======================================================================
// rmsnorm rows of D -> bf16 only
// ======================================================================
__global__ __launch_bounds__(256) void k_rms(const float* __restrict__ in,
                                             const float* __restrict__ w,
                                             us* __restrict__ outb) {
  int m = blockIdx.x, t = threadIdx.x;
  fv4 v = *(const fv4*)(in + (size_t)m * D + 4*t);
  float ss = v[0]*v[0] + v[1]*v[1] + v[2]*v[2] + v[3]*v[3];
#pragma unroll
  for (int off = 32; off > 0; off >>= 1) ss += __shfl_down(ss, off);
  __shared__ float buf[4];
  if ((t & 63) == 0) buf[t >> 6] = ss;
  __syncthreads();
  float tot = buf[0] + buf[1] + buf[2] + buf[3];
  float r = rsqrtf(tot * (1.0f / (float)D) + 1e-6f);
  fv4 wv = *(const fv4*)(w + 4*t);
  fv4 res = v * r * wv;
  us4 o; o[0]=f2bf(res[0]); o[1]=f2bf(res[1]); o[2]=f2bf(res[2]); o[3]=f2bf(res[3]);
  *(us4*)(outb + (size_t)m * D + 4*t) = o;
}

// ======================================================================
// FUSED rmsnorm + gamma gate (norm1 path), bf16 out only.
// ======================================================================
__global__ __launch_bounds__(256) void k_rmsg(const float* __restrict__ in,
                                              const float* __restrict__ w,
                                              const float* __restrict__ w1,
                                              const float* __restrict__ w2,
                                              us* __restrict__ outb,
                                              float* __restrict__ gko) {
  int m = blockIdx.x, t = threadIdx.x;
  __shared__ float hrow[D];
  __shared__ float buf[4];
  __shared__ float part[4][64];
  fv4 v = *(const fv4*)(in + (size_t)m * D + 4*t);
  float ss = v[0]*v[0] + v[1]*v[1] + v[2]*v[2] + v[3]*v[3];
#pragma unroll
  for (int off = 32; off > 0; off >>= 1) ss += __shfl_down(ss, off);
  if ((t & 63) == 0) buf[t >> 6] = ss;
  __syncthreads();
  float tot = buf[0] + buf[1] + buf[2] + buf[3];
  float r = rsqrtf(tot * (1.0f / (float)D) + 1e-6f);
  fv4 wv = *(const fv4*)(w + 4*t);
  fv4 res = v * r * wv;
  us4 o; o[0]=f2bf(res[0]); o[1]=f2bf(res[1]); o[2]=f2bf(res[2]); o[3]=f2bf(res[3]);
  *(us4*)(outb + (size_t)m * D + 4*t) = o;
  *(fv4*)&hrow[4*t] = res;
  __syncthreads();
  int oo = t & 63, seg = t >> 6;
  const float* wr = w1 + (size_t)oo * D + seg * 256;
  const float* hr = hrow + seg * 256;
  float acc = 0.f;
  for (int j = 0; j < 256; j += 4) {
    fv4 wv4 = *(const fv4*)(wr + j);
    acc += wv4[0]*hr[j] + wv4[1]*hr[j+1] + wv4[2]*hr[j+2] + wv4[3]*hr[j+3];
  }
  part[seg][oo] = acc;
  __syncthreads();
  if (t < 64) {
    float dot = part[0][t] + part[1][t] + part[2][t] + part[3][t];
    float sv = dot / (1.f + expf(-dot));
    float val = sv * w2[t];
#pragma unroll
    for (int off = 32; off > 0; off >>= 1) val += __shfl_down(val, off);
    if (t == 0) gko[m] = 1.f / (1.f + expf(-val));
  }
}

// ======================================================================
// flat f32 -> bf16 convert
// ======================================================================
__global__ __launch_bounds__(256) void k_cvt(const float* __restrict__ src,
                                             us* __restrict__ dst, int n) {
  for (size_t i = ((size_t)blockIdx.x * 256 + threadIdx.x) * 4; i < (size_t)n;
       i += (size_t)gridDim.x * 1024) {
    fv4 v = *(const fv4*)(src + i);
    us4 o; o[0]=f2bf(v[0]); o[1]=f2bf(v[1]); o[2]=f2bf(v[2]); o[3]=f2bf(v[3]);
    *(us4*)(dst + i) = o;
  }
}

// ======================================================================
// per-layer weight conversion, single launch
// ======================================================================
#define CVT_N1 786432   // 3*D*D/4
#define CVT_N2 262144   // D*D/4
#define CVT_N3 698880   // FF*D/4
#define CVT_N4 698880
#define CVT_N5 704512   // D * FFP/4
__global__ __launch_bounds__(256) void k_cvtw(const float* __restrict__ s1,
                                              const float* __restrict__ s2,
                                              const float* __restrict__ s3,
                                              const float* __restrict__ s4,
                                              const float* __restrict__ s5,
                                              us* __restrict__ d1, us* __restrict__ d2,
                                              us* __restrict__ d3, us* __restrict__ d4,
                                              us* __restrict__ d5) {
  const int TOT = CVT_N1 + CVT_N2 + CVT_N3 + CVT_N4 + CVT_N5;
  for (int i = blockIdx.x * 256 + threadIdx.x; i < TOT; i += gridDim.x * 256) {
    const float* s; us* d; int j = i;
    if (j < CVT_N1) { s = s1; d = d1; }
    else if ((j -= CVT_N1) < CVT_N2) { s = s2; d = d2; }
    else if ((j -= CVT_N2) < CVT_N3) { s = s3; d = d3; }
    else if ((j -= CVT_N3) < CVT_N4) { s = s4; d = d4; }
    else {
      j -= CVT_N4;
      int r = j / (FFP/4), c = (j % (FFP/4)) * 4;
      us4 o;
#pragma unroll
      for (int q = 0; q < 4; q++) {
        int cc = c + q;
        o[q] = (cc < FF) ? f2bf(s5[(size_t)r * FF + cc]) : (us)0;
      }
      *(us4*)&d5[(size_t)r * FFP + c] = o;
      continue;
    }
    fv4 v = *(const fv4*)(s + (size_t)4 * j);
    us4 o; o[0]=f2bf(v[0]); o[1]=f2bf(v[1]); o[2]=f2bf(v[2]); o[3]=f2bf(v[3]);
    *(us4*)&d[(size_t)4 * j] = o;
  }
}

// ======================================================================
// PIPELINED bf16 MFMA GEMM (g8 discipline).
// ======================================================================
template<int ACW, int BCW>
__device__ __forceinline__ void pg_stage(const us* __restrict__ A,
                                         const us* __restrict__ W,
                                         us* bufA, us* bufB,
                                         int m0, int n0, int Nn, int Kk,
                                         int tile, int w, int lane, int lr, int sx) {
#pragma unroll
  for (int i = 0; i < ACW; i++) {
    int chunk = w * ACW + i;
    G2L16(A + (size_t)(m0 + chunk*8 + lr) * Kk + tile*64 + sx, bufA + chunk*512 + lane*8);
  }
#pragma unroll
  for (int i = 0; i < BCW; i++) {
    int chunk = w * BCW + i;
    int wrow = n0 + chunk*8 + lr;
    if (wrow >= Nn) wrow = Nn - 1;
    G2L16(W + (size_t)wrow * Kk + tile*64 + sx, bufB + chunk*512 + lane*8);
  }
}

template<int EPI, int BM, int BN>
__global__ __launch_bounds__(256) void k_pgemm(const us* __restrict__ A,
                                               const us* __restrict__ W,
                                               float* __restrict__ C,
                                               int Nn, int Kk) {
  constexpr int FM = BM / 32, FN = BN / 32;
  constexpr int ACW = BM / 32, BCW = BN / 32;
  constexpr int L = ACW + BCW;
  __shared__ __attribute__((aligned(16))) us lds[2][(BM + BN) * 64];
  int t = threadIdx.x, lane = t & 63, w = t >> 6;
  int l16 = lane & 15, lkb = lane >> 4, lr = lane >> 3;
  int sx = ((lane & 7) ^ lr) * 8;
  int sw = l16 & 7;
  int gx = gridDim.x, nwg = gx * gridDim.y;
  int nf = xcd_remap(blockIdx.y * gx + blockIdx.x, nwg);
  int m0 = (nf % gx) * BM, n0 = (nf / gx) * BN;
  int wr = w >> 1, wc = w & 1;
  int NK = Kk >> 6;

  pg_stage<ACW,BCW>(A, W, lds[0], lds[0] + BM*64, m0, n0, Nn, Kk, 0, w, lane, lr, sx);
  pg_stage<ACW,BCW>(A, W, lds[1], lds[1] + BM*64, m0, n0, Nn, Kk, 1, w, lane, lr, sx);

  fv4 acc[FM][FN] = {};
  for (int T = 0; T < NK; T++) {
    if (T == NK - 1) waitcnt_vm<0>(); else waitcnt_vm<L>();
    __builtin_amdgcn_s_barrier();
    const us* bufA = lds[T & 1];
    const us* bufB = bufA + BM*64;
    bf16x8 af[2][FM], bfh[2][FN];
#pragma unroll
    for (int kk = 0; kk < 2; kk++) {
#pragma unroll
      for (int i = 0; i < FM; i++)
        af[kk][i] = *(const bf16x8*)&bufA[(wr*(BM/2) + i*16 + l16)*64 + (((kk*4+lkb)) ^ sw)*8];
#pragma unroll
      for (int j = 0; j < FN; j++)
        bfh[kk][j] = *(const bf16x8*)&bufB[(wc*(BN/2) + j*16 + l16)*64 + (((kk*4+lkb)) ^ sw)*8];
    }
    __builtin_amdgcn_s_barrier();
    if (T + 2 < NK)
      pg_stage<ACW,BCW>(A, W, lds[T & 1], lds[T & 1] + BM*64, m0, n0, Nn, Kk, T + 2, w, lane, lr, sx);
    __builtin_amdgcn_s_setprio(1);
#pragma unroll
    for (int kk = 0; kk < 2; kk++)
#pragma unroll
      for (int i = 0; i < FM; i++)
#pragma unroll
        for (int j = 0; j < FN; j++)
          acc[i][j] = MFMA16(af[kk][i], bfh[kk][j], acc[i][j], 0, 0, 0);
    __builtin_amdgcn_s_setprio(0);
  }

#pragma unroll
  for (int i = 0; i < FM; i++) {
    int gr0 = m0 + wr*(BM/2) + i*16 + lkb*4;
#pragma unroll
    for (int j = 0; j < FN; j++) {
      int gc = n0 + wc*(BN/2) + j*16 + l16;
      if (gc < Nn) {
#pragma unroll
        for (int r = 0; r < 4; r++) {
          size_t idx = (size_t)(gr0 + r) * Nn + gc;
          float val = acc[i][j][r];
          if (EPI == 0) C[idx] = val;
          else C[idx] += val;
        }
      }
    }
  }
}

// ======================================================================
// PIPELINED fused FFN w1/w2 GEMM (dual-B), 128x64, L=8.
// ======================================================================
__device__ __forceinline__ void pf_stage(const us* __restrict__ A,
                                         const us* __restrict__ W1,
                                         const us* __restrict__ W2,
                                         us* buf, int m0, int n0, int Nn, int Kk,
                                         int tile, int w, int lane, int lr, int sx) {
#pragma unroll
  for (int i = 0; i < 4; i++) {
    int chunk = w * 4 + i;
    G2L16(A + (size_t)(m0 + chunk*8 + lr) * Kk + tile*64 + sx, buf + chunk*512 + lane*8);
  }
#pragma unroll
  for (int i = 0; i < 2; i++) {
    int chunk = w * 2 + i;
    int wrow = n0 + chunk*8 + lr;
    if (wrow >= Nn) wrow = Nn - 1;
    G2L16(W1 + (size_t)wrow * Kk + tile*64 + sx, buf + 8192 + chunk*512 + lane*8);
    G2L16(W2 + (size_t)wrow * Kk + tile*64 + sx, buf + 12288 + chunk*512 + lane*8);
  }
}

__global__ __launch_bounds__(256) void k_pffn12(const us* __restrict__ A,
                                                const us* __restrict__ W1,
                                                const us* __restrict__ W2,
                                                us* __restrict__ Cb,
                                                int Nn, int Kk) {
  __shared__ __attribute__((aligned(16))) us lds[2][16384];
  int t = threadIdx.x, lane = t & 63, w = t >> 6;
  int l16 = lane & 15, lkb = lane >> 4, lr = lane >> 3;
  int sx = ((lane & 7) ^ lr) * 8;
  int sw = l16 & 7;
  int gx = gridDim.x, nwg = gx * gridDim.y;
  int nf = xcd_remap(blockIdx.y * gx + blockIdx.x, nwg);
  int m0 = (nf % gx) * 128, n0 = (nf / gx) * 64;
  int wr = w >> 1, wc = w & 1;
  int NK = Kk >> 6;

  pf_stage(A, W1, W2, lds[0], m0, n0, Nn, Kk, 0, w, lane, lr, sx);
  pf_stage(A, W1, W2, lds[1], m0, n0, Nn, Kk, 1, w, lane, lr, sx);

  fv4 acc1[4][2] = {}, acc2[4][2] = {};
  for (int T = 0; T < NK; T++) {
    if (T == NK - 1) waitcnt_vm<0>(); else waitcnt_vm<8>();
    __builtin_amdgcn_s_barrier();
    const us* buf = lds[T & 1];
    bf16x8 af[2][4], b1f[2][2], b2f[2][2];
#pragma unroll
    for (int kk = 0; kk < 2; kk++) {
#pragma unroll
      for (int i = 0; i < 4; i++)
        af[kk][i] = *(const bf16x8*)&buf[(wr*64 + i*16 + l16)*64 + ((kk*4+lkb) ^ sw)*8];
#pragma unroll
      for (int j = 0; j < 2; j++) {
        b1f[kk][j] = *(const bf16x8*)&buf[8192  + (wc*32 + j*16 + l16)*64 + ((kk*4+lkb) ^ sw)*8];
        b2f[kk][j] = *(const bf16x8*)&buf[12288 + (wc*32 + j*16 + l16)*64 + ((kk*4+lkb) ^ sw)*8];
      }
    }
    __builtin_amdgcn_s_barrier();
    if (T + 2 < NK)
      pf_stage(A, W1, W2, lds[T & 1], m0, n0, Nn, Kk, T + 2, w, lane, lr, sx);
    __builtin_amdgcn_s_setprio(1);
#pragma unroll
    for (int kk = 0; kk < 2; kk++)
#pragma unroll
      for (int i = 0; i < 4; i++)
#pragma unroll
        for (int j = 0; j < 2; j++) {
          acc1[i][j] = MFMA16(af[kk][i], b1f[kk][j], acc1[i][j], 0, 0, 0);
          acc2[i][j] = MFMA16(af[kk][i], b2f[kk][j], acc2[i][j], 0, 0, 0);
        }
    __builtin_amdgcn_s_setprio(0);
  }

#pragma unroll
  for (int i = 0; i < 4; i++) {
    int gr0 = m0 + wr*64 + i*16 + lkb*4;
#pragma unroll
    for (int j = 0; j < 2; j++) {
      int gc = n0 + wc*32 + j*16 + l16;
      if (gc < Nn) {
#pragma unroll
        for (int r = 0; r < 4; r++) {
          float v1 = acc1[i][j][r], v2 = acc2[i][j][r];
          float sv = v1 / (1.f + expf(-v1));
          Cb[(size_t)(gr0 + r) * FFP + gc] = f2bf(sv * v2);
        }
      }
    }
  }
}

// ======================================================================
// PIPELINED qkv GEMM + head-split + qk-rmsnorm + rope epilogue.
// ======================================================================
__global__ __launch_bounds__(256) void k_pqkv(const us* __restrict__ A,
                                              const us* __restrict__ W,
                                              const float* __restrict__ qnw,
                                              const float* __restrict__ knw,
                                              const float* __restrict__ cosT,
                                              const float* __restrict__ sinT,
                                              us* __restrict__ qb,
                                              us* __restrict__ kb,
                                              us* __restrict__ vb) {
  const int Kk = D, Nn = 3 * D;
  __shared__ __attribute__((aligned(16))) us lds[2][16384];
  int t = threadIdx.x, lane = t & 63, w = t >> 6;
  int l16 = lane & 15, lkb = lane >> 4, lr = lane >> 3;
  int sx = ((lane & 7) ^ lr) * 8;
  int sw = l16 & 7;
  int gx = gridDim.x, nwg = gx * gridDim.y;
  int nf = xcd_remap(blockIdx.y * gx + blockIdx.x, nwg);
  int m0 = (nf % gx) * 128, n0 = (nf / gx) * 128;
  int wr = w >> 1, wc = w & 1;
  int NK = Kk >> 6;

  pg_stage<4,4>(A, W, lds[0], lds[0] + 8192, m0, n0, Nn, Kk, 0, w, lane, lr, sx);
  pg_stage<4,4>(A, W, lds[1], lds[1] + 8192, m0, n0, Nn, Kk, 1, w, lane, lr, sx);

  fv4 acc[4][4] = {};
  for (int T = 0; T < NK; T++) {
    if (T == NK - 1) waitcnt_vm<0>(); else waitcnt_vm<8>();
    __builtin_amdgcn_s_barrier();
    const us* bufA = lds[T & 1];
    const us* bufB = bufA + 8192;
    bf16x8 af[2][4], bfh[2][4];
#pragma unroll
    for (int kk = 0; kk < 2; kk++) {
#pragma unroll
      for (int i = 0; i < 4; i++) {
        af[kk][i]  = *(const bf16x8*)&bufA[(wr*64 + i*16 + l16)*64 + ((kk*4+lkb) ^ sw)*8];
        bfh[kk][i] = *(const bf16x8*)&bufB[(wc*64 + i*16 + l16)*64 + ((kk*4+lkb) ^ sw)*8];
      }
    }
    __builtin_amdgcn_s_barrier();
    if (T + 2 < NK)
      pg_stage<4,4>(A, W, lds[T & 1], lds[T & 1] + 8192, m0, n0, Nn, Kk, T + 2, w, lane, lr, sx);
    __builtin_amdgcn_s_setprio(1);
#pragma unroll
    for (int kk = 0; kk < 2; kk++)
#pragma unroll
      for (int i = 0; i < 4; i++)
#pragma unroll
        for (int j = 0; j < 4; j++)
          acc[i][j] = MFMA16(af[kk][i], bfh[kk][j], acc[i][j], 0, 0, 0);
    __builtin_amdgcn_s_setprio(0);
  }

  // ---- fused epilogue ----
  int part = n0 >> 10;
  int hd = ((n0 & 1023) + wc * 64) >> 6;
  us* dst = (part == 0) ? qb : ((part == 1) ? kb : vb);
  if (part == 2) {
#pragma unroll
    for (int i = 0; i < 4; i++)
#pragma unroll
      for (int r = 0; r < 4; r++) {
        int m = m0 + wr*64 + i*16 + lkb*4 + r;
        int b = m >> 10, s = m & 1023;
        us* drow = dst + (((size_t)(b*H + hd)) * S + s) * 64;
#pragma unroll
        for (int j = 0; j < 4; j++) drow[j*16 + l16] = f2bf(acc[i][j][r]);
      }
  } else {
    const float* nw = (part == 0) ? qnw : knw;
    float w0 = nw[l16], w1 = nw[16 + l16], w2 = nw[32 + l16], w3 = nw[48 + l16];
#pragma unroll
    for (int i = 0; i < 4; i++)
#pragma unroll
      for (int r = 0; r < 4; r++) {
        int m = m0 + wr*64 + i*16 + lkb*4 + r;
        int b = m >> 10, s = m & 1023;
        float a0 = acc[i][0][r], a1 = acc[i][1][r], a2 = acc[i][2][r], a3 = acc[i][3][r];
        float s2 = a0*a0 + a1*a1 + a2*a2 + a3*a3;
        s2 += __shfl_xor(s2, 1); s2 += __shfl_xor(s2, 2);
        s2 += __shfl_xor(s2, 4); s2 += __shfl_xor(s2, 8);
        float rs = rsqrtf(s2 * (1.0f / (float)DH) + 1e-6f);
        float v0 = a0 * rs * w0, v1 = a1 * rs * w1, v2 = a2 * rs * w2, v3 = a3 * rs * w3;
        float c0 = cosT[s*32 + l16],      sn0 = sinT[s*32 + l16];
        float c1 = cosT[s*32 + 16 + l16], sn1 = sinT[s*32 + 16 + l16];
        us* drow = dst + (((size_t)(b*H + hd)) * S + s) * 64;
        drow[l16]      = f2bf(v0 * c0 - v2 * sn0);
        drow[16 + l16] = f2bf(v1 * c1 - v3 * sn1);
        drow[32 + l16] = f2bf(v2 * c0 + v0 * sn0);
        drow[48 + l16] = f2bf(v3 * c1 + v1 * sn1);
      }
  }
}

// ======================================================================
// 256x256 8-wave deep-pipelined bf16 GEMM — lm_head (unchanged).
// ======================================================================
struct G8 { const us* A; const us* W; int K; int m0; int n0; };

__device__ __forceinline__ void g8_issue(const G8& g, us* lds8, int q, int t) {
  int tile = q >> 2, h = q & 3;
  us* buf = lds8 + (size_t)(tile & 1) * 32768;
  const us* Gp = (h < 2) ? g.A : g.W;
  int rbase = ((h < 2) ? g.m0 : g.n0) + (h & 1) * 128;
  us* part = buf + (h >> 1) * 16384 + (h & 1) * 8192;
  int r8 = t >> 3;
  int sl = (((t & 7) ^ (r8 & 7)) * 8);
#pragma unroll
  for (int c = 0; c < 2; c++) {
    const us* src = Gp + (size_t)(rbase + c * 64 + r8) * g.K + tile * 64 + sl;
    us* dst = part + c * 4096 + t * 8;
    G2L16(src, dst);
  }
}

__global__ __launch_bounds__(512, 2) void k_gemm8(const us* __restrict__ A,
                                                  const us* __restrict__ W,
                                                  float* __restrict__ C,
                                                  int Nn, int Kk) {
  __shared__ __attribute__((aligned(16))) us lds8[65536];
  int t = threadIdx.x, lane = t & 63, w = t >> 6;
  int wm = w >> 2, wn = w & 3;
  int l16 = lane & 15, lkb = lane >> 4;
  int gx = gridDim.x, nwg = gx * gridDim.y;
  int nf = xcd_remap(blockIdx.y * gx + blockIdx.x, nwg);
  int m0 = (nf % gx) * 256, n0 = (nf / gx) * 256;
  G8 g{A, W, Kk, m0, n0};
  int NK = Kk >> 6, QMAX = NK * 4;

  int q = 0;
  for (; q < 7 && q < QMAX; ++q) g8_issue(g, lds8, q, t);

  fv4 acc[8][4] = {};
  int arow = wm * 128 + l16;
  int brow = wn * 64 + l16;
  int sw = l16 & 7;

  for (int T = 0; T < NK; ++T) {
    if (q < QMAX) { g8_issue(g, lds8, q, t); q++; }
    if (T == NK - 1) asm volatile("s_waitcnt vmcnt(0)" ::: "memory");
    else             asm volatile("s_waitcnt vmcnt(8)" ::: "memory");
    __builtin_amdgcn_s_barrier();
    const us* buf = lds8 + (size_t)(T & 1) * 32768;
    bf16x8 a0[8], a1[8], b0[4], b1[4];
#pragma unroll
    for (int i = 0; i < 8; i++) {
      a0[i] = *(const bf16x8*)&buf[(arow + i*16)*64 + ((lkb     ) ^ sw)*8];
      a1[i] = *(const bf16x8*)&buf[(arow + i*16)*64 + ((lkb +  4) ^ sw)*8];
    }
#pragma unroll
    for (int j = 0; j < 4; j++) {
      b0[j] = *(const bf16x8*)&buf[16384 + (brow + j*16)*64 + ((lkb    ) ^ sw)*8];
      b1[j] = *(const bf16x8*)&buf[16384 + (brow + j*16)*64 + ((lkb + 4) ^ sw)*8];
    }
    __builtin_amdgcn_s_barrier();
    __builtin_amdgcn_s_setprio(1);
#pragma unroll
    for (int i = 0; i < 8; i++)
#pragma unroll
      for (int j = 0; j < 4; j++)
        acc[i][j] = MFMA16(a0[i], b0[j], acc[i][j], 0, 0, 0);
    __builtin_amdgcn_s_setprio(0);
    if (q < QMAX) { g8_issue(g, lds8, q, t); q++; }
    if (q < QMAX) { g8_issue(g, lds8, q, t); q++; }
    if (q < QMAX) { g8_issue(g, lds8, q, t); q++; }
    __builtin_amdgcn_s_setprio(1);
#pragma unroll
    for (int i = 0; i < 8; i++)
#pragma unroll
      for (int j = 0; j < 4; j++)
        acc[i][j] = MFMA16(a1[i], b1[j], acc[i][j], 0, 0, 0);
    __builtin_amdgcn_s_setprio(0);
  }

#pragma unroll
  for (int i = 0; i < 8; i++) {
    int gr0 = m0 + wm*128 + i*16 + lkb*4;
#pragma unroll
    for (int j = 0; j < 4; j++) {
      int gc = n0 + wn*64 + j*16 + l16;
#pragma unroll
      for (int r = 0; r < 4; r++)
        C[(size_t)(gr0 + r) * Nn + gc] = acc[i][j][r];
    }
  }
}

// ======================================================================
// 64x64 bf16 transpose: (bh, s, dh) -> (bh, dh, s); grid.z selects k or v
// ======================================================================
__global__ __launch_bounds__(256) void k_tr2(const us* __restrict__ ksrc,
                                             const us* __restrict__ vsrc,
                                             us* __restrict__ kdst,
                                             us* __restrict__ vdst) {
  __shared__ __attribute__((aligned(16))) us tile[64*72];
  int st = blockIdx.x, bh = blockIdx.y, t = threadIdx.x;
  const us* src = blockIdx.z ? vsrc : ksrc;
  us* dst = blockIdx.z ? vdst : kdst;
  const us* sp = src + ((size_t)bh * S + st*64) * 64;
#pragma unroll
  for (int p = 0; p < 2; p++) {
    int idx = t + p*256;
    int r = idx >> 3, c = (idx & 7)*8;
    *(bf16x8*)&tile[r*72 + c] = *(const bf16x8*)&sp[(size_t)idx*8];
  }
  __syncthreads();
  int d = t >> 2;
#pragma unroll
  for (int cc = 0; cc < 16; cc += 8) {
    int s0 = (t & 3)*16 + cc;
    bf16x8 vv;
#pragma unroll
    for (int j2 = 0; j2 < 8; j2++) vv[j2] = (short)tile[(s0+j2)*72 + d];
    *(bf16x8*)&dst[((size_t)bh*64 + d)*S + st*64 + s0] = vv;
  }
}

// ======================================================================
// FUSED omega-memory + flash attention — pipelined staging + IN-BLOCK
// gk prefix scan.
// ======================================================================
#define SM_OFF 24.0f

__device__ __forceinline__ void m_stage(const us* __restrict__ src, int rstride,
                                        us* buf, int w, int lane, int lr, int sx8) {
#pragma unroll
  for (int i = 0; i < 2; i++) {
    int rbase = i * 32 + w * 8;
    G2L16(src + (size_t)(rbase + lr) * rstride + sx8, buf + rbase * 64 + lane * 8);
  }
}

__global__ __launch_bounds__(256) void k_matt(const us* __restrict__ qb,
                                              const us* __restrict__ kb,
                                              const us* __restrict__ kbT,
                                              const us* __restrict__ vbT,
                                              const us* __restrict__ MpB,
                                              const float* __restrict__ gk,
                                              const float* __restrict__ mg, int layer,
                                              us* __restrict__ ob) {
  int nf = xcd_remap(blockIdx.y * 8 + blockIdx.x, 256);
  int xx = nf & 7, bh = nf >> 3;
  int b = bh >> 4, hh = bh & 15;
  int t = threadIdx.x, lane = t & 63, w = t >> 6;
  int l16 = lane & 15, lg = lane >> 4, lr = lane >> 3;
  int sx8 = ((lane & 7) ^ lr) * 8;
  int sw = l16 & 7;

  __shared__ __attribute__((aligned(16))) us Qs[64*72];
  __shared__ __attribute__((aligned(16))) us Ms[64*72];
  __shared__ __attribute__((aligned(16))) us Ps[64*72];
  __shared__ __attribute__((aligned(16))) us KT[2][2][64*64];
  __shared__ float gkL[S], nrmL[S];
  __shared__ float wsum2[4];

  float gate = 1.f / (1.f + expf(-mg[layer]));
  const us* kbB = kb + (size_t)bh * S * 64;
  const us* ktB = kbT + (size_t)bh * 64 * S;
  const us* vtB = vbT + (size_t)bh * 64 * S;

  // ---- once per block: Mp, gk row, and in-block prefix scan ----
  {
    const us* mp = MpB + (size_t)hh * 4096;
#pragma unroll
    for (int p = 0; p < 2; p++) {
      int idx = t + p*256;
      int r = idx >> 3, c = (idx & 7) * 8;
      *(bf16x8*)&Ms[r*72 + c] = *(const bf16x8*)&mp[(size_t)idx*8];
    }
#pragma unroll
    for (int p = 0; p < 4; p++) gkL[t + p*256] = gk[b*S + t + p*256];
  }
  __syncthreads();
  {
    float v0 = gkL[4*t], v1 = gkL[4*t+1], v2 = gkL[4*t+2], v3 = gkL[4*t+3];
    float r0 = v0, r1 = r0 + v1, r2 = r1 + v2, r3 = r2 + v3;
    float s = r3;
#pragma unroll
    for (int off = 1; off < 64; off <<= 1) {
      float y = __shfl_up(s, off, 64);
      if (lane >= off) s += y;
    }
    if (lane == 63) wsum2[w] = s;
    __syncthreads();
    float wexcl = 0.f;
    if (w == 1) wexcl = wsum2[0];
    else if (w == 2) wexcl = wsum2[0] + wsum2[1];
    else if (w == 3) wexcl = wsum2[0] + wsum2[1] + wsum2[2];
    float base = wexcl + (s - r3);
    nrmL[4*t]   = (float)NP + base + r0;
    nrmL[4*t+1] = (float)NP + base + r1;
    nrmL[4*t+2] = (float)NP + base + r2;
    nrmL[4*t+3] = (float)NP + base + r3;
  }

  for (int sel = 0; sel < 2; sel++) {
    int qt = sel ? (15 - xx) : xx;
    __syncthreads();
    {
      const us* src = qb + ((size_t)bh * S + qt*64) * 64;
#pragma unroll
      for (int p = 0; p < 2; p++) {
        int idx = t + p*256;
        int r = idx >> 3, c = (idx & 7) * 8;
        *(bf16x8*)&Qs[r*72 + c] = *(const bf16x8*)&src[(size_t)idx*8];
      }
    }
    __syncthreads();

    bf16x8 aq0 = *(const bf16x8*)&Qs[(16*w + l16)*72 + lg*8];
    bf16x8 aq1 = *(const bf16x8*)&Qs[(16*w + l16)*72 + 32 + lg*8];

    fv4 am[4];
#pragma unroll
    for (int j = 0; j < 4; j++) {
      bf16x8 b0 = *(const bf16x8*)&Ms[(16*j + l16)*72 + lg*8];
      bf16x8 b1 = *(const bf16x8*)&Ms[(16*j + l16)*72 + 32 + lg*8];
      fv4 z = {};
      z = MFMA16(aq0, b0, z, 0, 0, 0);
      z = MFMA16(aq1, b1, z, 0, 0, 0);
      am[j] = z;
    }

    // ======== phase 1: omega memory (pipelined K + K^T) ========
    m_stage(kbB,            64, KT[0][0], w, lane, lr, sx8);
    m_stage(ktB,            S,  KT[0][1], w, lane, lr, sx8);
    m_stage(kbB + 4096,     64, KT[1][0], w, lane, lr, sx8);
    m_stage(ktB + 64,       S,  KT[1][1], w, lane, lr, sx8);
    for (int kt = 0; kt <= qt; kt++) {
      int ks = kt * 64;
      if (kt == qt) waitcnt_vm<0>(); else waitcnt_vm<4>();
      __builtin_amdgcn_s_barrier();
      const us* bK = KT[kt & 1][0];
      const us* bT = KT[kt & 1][1];
      bf16x8 kf0[4], kf1[4], tf0[4], tf1[4];
      float gv[4];
#pragma unroll
      for (int j = 0; j < 4; j++) {
        int row = 16*j + l16;
        kf0[j] = *(const bf16x8*)&bK[row*64 + ((lg    ) ^ sw)*8];
        kf1[j] = *(const bf16x8*)&bK[row*64 + ((lg + 4) ^ sw)*8];
        tf0[j] = *(const bf16x8*)&bT[row*64 + ((lg    ) ^ sw)*8];
        tf1[j] = *(const bf16x8*)&bT[row*64 + ((lg + 4) ^ sw)*8];
        gv[j] = gkL[ks + row];
      }
      __builtin_amdgcn_s_barrier();
      if (kt + 2 <= qt) {
        m_stage(kbB + (size_t)(kt+2)*4096, 64, KT[kt & 1][0], w, lane, lr, sx8);
        m_stage(ktB + (kt+2)*64,           S,  KT[kt & 1][1], w, lane, lr, sx8);
      }
      fv4 sc[4];
      __builtin_amdgcn_s_setprio(1);
#pragma unroll
      for (int j = 0; j < 4; j++) {
        fv4 z = {};
        z = MFMA16(aq0, kf0[j], z, 0, 0, 0);
        z = MFMA16(aq1, kf1[j], z, 0, 0, 0);
        sc[j] = z;
      }
      __builtin_amdgcn_s_setprio(0);
      if (kt < qt) {
#pragma unroll
        for (int j = 0; j < 4; j++)
#pragma unroll
          for (int r = 0; r < 4; r++)
            Ps[(16*w + lg*4 + r)*72 + 16*j + l16] = f2bf(sc[j][r] * gv[j]);
      } else {
#pragma unroll
        for (int j = 0; j < 4; j++) {
          int kj = 16*j + l16;
#pragma unroll
          for (int r = 0; r < 4; r++) {
            int qi = 16*w + lg*4 + r;
            Ps[qi*72 + kj] = (kj > qi) ? (us)0 : f2bf(sc[j][r] * gv[j]);
          }
        }
      }
      bf16x8 ap0 = *(const bf16x8*)&Ps[(16*w + l16)*72 + lg*8];
      bf16x8 ap1 = *(const bf16x8*)&Ps[(16*w + l16)*72 + 32 + lg*8];
      __builtin_amdgcn_s_setprio(1);
#pragma unroll
      for (int j = 0; j < 4; j++) {
        am[j] = MFMA16(ap0, tf0[j], am[j], 0, 0, 0);
        am[j] = MFMA16(ap1, tf1[j], am[j], 0, 0, 0);
      }
      __builtin_amdgcn_s_setprio(0);
    }

    // q' update: Qs rows wave-private -> no barriers
#pragma unroll
    for (int j = 0; j < 4; j++)
#pragma unroll
      for (int r = 0; r < 4; r++) {
        int qi = 16*w + lg*4 + r, dj = 16*j + l16;
        float qold = bf2f(Qs[qi*72 + dj]);
        float qn = (1.f - gate) * qold + gate * (am[j][r] / nrmL[qt*64 + qi]);
        Qs[qi*72 + dj] = f2bf(qn);
      }
    aq0 = *(const bf16x8*)&Qs[(16*w + l16)*72 + lg*8];
    aq1 = *(const bf16x8*)&Qs[(16*w + l16)*72 + 32 + lg*8];

    // ======== phase 2: flash attention (pipelined K + V^T) ========
    float lsum[4] = {};
    fv4 ao[4] = {};
    m_stage(kbB,            64, KT[0][0], w, lane, lr, sx8);
    m_stage(vtB,            S,  KT[0][1], w, lane, lr, sx8);
    m_stage(kbB + 4096,     64, KT[1][0], w, lane, lr, sx8);
    m_stage(vtB + 64,       S,  KT[1][1], w, lane, lr, sx8);
    for (int kt = 0; kt <= qt; kt++) {
      if (kt == qt) waitcnt_vm<0>(); else waitcnt_vm<4>();
      __builtin_amdgcn_s_barrier();
      const us* bK = KT[kt & 1][0];
      const us* bV = KT[kt & 1][1];
      bf16x8 kf0[4], kf1[4], vf0[4], vf1[4];
#pragma unroll
      for (int j = 0; j < 4; j++) {
        int row = 16*j + l16;
        kf0[j] = *(const bf16x8*)&bK[row*64 + ((lg    ) ^ sw)*8];
        kf1[j] = *(const bf16x8*)&bK[row*64 + ((lg + 4) ^ sw)*8];
        vf0[j] = *(const bf16x8*)&bV[row*64 + ((lg    ) ^ sw)*8];
        vf1[j] = *(const bf16x8*)&bV[row*64 + ((lg + 4) ^ sw)*8];
      }
      __builtin_amdgcn_s_barrier();
      if (kt + 2 <= qt) {
        m_stage(kbB + (size_t)(kt+2)*4096, 64, KT[kt & 1][0], w, lane, lr, sx8);
        m_stage(vtB + (kt+2)*64,           S,  KT[kt & 1][1], w, lane, lr, sx8);
      }
      fv4 sc[4];
      __builtin_amdgcn_s_setprio(1);
#pragma unroll
      for (int j = 0; j < 4; j++) {
        fv4 z = {};
        z = MFMA16(aq0, kf0[j], z, 0, 0, 0);
        z = MFMA16(aq1, kf1[j], z, 0, 0, 0);
        sc[j] = z;
      }
      __builtin_amdgcn_s_setprio(0);
      if (kt < qt) {
#pragma unroll
        for (int j = 0; j < 4; j++)
#pragma unroll
          for (int r = 0; r < 4; r++) {
            float p = __expf(fmaf(sc[j][r], 0.125f, -SM_OFF));
            lsum[r] += p;
            Ps[(16*w + lg*4 + r)*72 + 16*j + l16] = f2bf(p);
          }
      } else {
#pragma unroll
        for (int j = 0; j < 4; j++) {
          int kj = 16*j + l16;
#pragma unroll
          for (int r = 0; r < 4; r++) {
            int qi = 16*w + lg*4 + r;
            float p = (kj > qi) ? 0.f : __expf(fmaf(sc[j][r], 0.125f, -SM_OFF));
            lsum[r] += p;
            Ps[qi*72 + kj] = f2bf(p);
          }
        }
      }
      bf16x8 ap0 = *(const bf16x8*)&Ps[(16*w + l16)*72 + lg*8];
      bf16x8 ap1 = *(const bf16x8*)&Ps[(16*w + l16)*72 + 32 + lg*8];
      __builtin_amdgcn_s_setprio(1);
#pragma unroll
      for (int j = 0; j < 4; j++) {
        ao[j] = MFMA16(ap0, vf0[j], ao[j], 0, 0, 0);
        ao[j] = MFMA16(ap1, vf1[j], ao[j], 0, 0, 0);
      }
      __builtin_amdgcn_s_setprio(0);
    }

#pragma unroll
    for (int r = 0; r < 4; r++) {
      float l = lsum[r];
      l += __shfl_xor(l, 1);
      l += __shfl_xor(l, 2);
      l += __shfl_xor(l, 4);
      l += __shfl_xor(l, 8);
      lsum[r] = l;
    }
#pragma unroll
    for (int j = 0; j < 4; j++)
#pragma unroll
      for (int r = 0; r < 4; r++) {
        int qi = 16*w + lg*4 + r;
        ob[((size_t)b*S + qt*64 + qi) * D + hh*64 + 16*j + l16] = f2bf(ao[j][r] / lsum[r]);
      }
  }
}

// ======================================================================
// launcher
// ======================================================================
extern "C" void kernel_launch(void* const* d_in, const int* in_sizes, int n_in,
                              void* d_out, int out_size, void* d_ws, size_t ws_size,
                              hipStream_t stream) {
  const int*   ids      = (const int*)d_in[0];
  const float* tok_emb  = (const float*)d_in[1];
  const float* w_init   = (const float*)d_in[2];
  const float* persist  = (const float*)d_in[3];
  const float* norm1_w  = (const float*)d_in[4];
  const float* norm2_w  = (const float*)d_in[5];
  const float* norm_f_w = (const float*)d_in[6];
  const float* qkv_w    = (const float*)d_in[7];
  const float* q_norm_w = (const float*)d_in[8];
  const float* k_norm_w = (const float*)d_in[9];
  const float* gamma_w1 = (const float*)d_in[10];
  const float* gamma_w2 = (const float*)d_in[11];
  const float* mem_gate = (const float*)d_in[12];
  const float* w_o      = (const float*)d_in[13];
  const float* ffn_w1   = (const float*)d_in[14];
  const float* ffn_w2   = (const float*)d_in[15];
  const float* ffn_w3   = (const float*)d_in[16];
  float* out = (float*)d_out;

  // ---- workspace layout ----
  float* ws   = (float*)d_ws;
  float* x    = ws;                          // 2097152 f32
  us*    hbf  = (us*)(x + 2097152);          // 2097152 us
  float* gk   = x + 2097152 + 1048576;
  float* nrm  = gk + 2048;                   // dead slot
  float* cosT = nrm + 2048;
  float* sinT = cosT + 32768;
  us*    MpBH = (us*)(sinT + 32768);         // H*DH*DH us
  float* h    = sinT + 32768 + 65536;        // dead slot (temb alias base)
  float* qkv  = h + 2097152;                 // dead slot
  us*    obf  = (us*)(qkv + 6291456);        // 2097152 us
  us*    qb   = obf + 2097152;
  us*    kb   = qb + 2097152;
  us*    vb   = kb + 2097152;
  us*    kbT  = vb + 2097152;
  us*    vbT  = kbT + 2097152;
  us*    f1bf = vbT + 2097152;               // M*FFP = 5636096 us
  us*    wq   = f1bf + (size_t)M*FFP;        // 3145728
  us*    wo   = wq + 3145728;                // 1048576
  us*    w1c  = wo + 1048576;                // 2795520
  us*    w2c  = w1c + 2795520;               // 2795520
  us*    w3c  = w2c + 2795520;               // 2818048
  us*    temb = (us*)h;                      // aliases dead h..f1bf span

  k_embed<<<M, 256, 0, stream>>>(ids, tok_emb, w_init, x);
  k_rope_tables<<<(S*32 + 255)/256, 256, 0, stream>>>(cosT, sinT);
  k_mp<<<H, 256, 0, stream>>>(persist, MpBH);

  for (int l = 0; l < NL; l++) {
    k_cvtw<<<2048, 256, 0, stream>>>(qkv_w + (size_t)l*3*D*D, w_o + (size_t)l*D*D,
                                     ffn_w1 + (size_t)l*FF*D, ffn_w2 + (size_t)l*FF*D,
                                     ffn_w3 + (size_t)l*D*FF,
                                     wq, wo, w1c, w2c, w3c);
    k_rmsg<<<M, 256, 0, stream>>>(x, norm1_w + (size_t)l * D,
                                  gamma_w1 + (size_t)l*GH*D, gamma_w2 + (size_t)l*GH,
                                  hbf, gk);
    k_pqkv<<<dim3(16, 24), 256, 0, stream>>>(hbf, wq,
                                             q_norm_w + (size_t)l*DH, k_norm_w + (size_t)l*DH,
                                             cosT, sinT, qb, kb, vb);
    k_tr2<<<dim3(S/64, B*H, 2), 256, 0, stream>>>(kb, vb, kbT, vbT);
    k_matt<<<dim3(8, B*H), 256, 0, stream>>>(qb, kb, kbT, vbT, MpBH, gk, mem_gate, l, obf);
    k_pgemm<2,64,64><<<dim3(M/64, D/64), 256, 0, stream>>>(obf, wo, x, D, D);
    k_rms<<<M, 256, 0, stream>>>(x, norm2_w + (size_t)l * D, hbf);
    k_pffn12<<<dim3(M/128, (FF+63)/64), 256, 0, stream>>>(hbf, w1c, w2c, f1bf, FF, D);
    k_pgemm<2,64,64><<<dim3(M/64, D/64), 256, 0, stream>>>(f1bf, w3c, x, D, FFP);
  }

  k_rms<<<M, 256, 0, stream>>>(x, norm_f_w, hbf);
  k_cvt<<<2048, 256, 0, stream>>>(tok_emb, temb, V*D);
  k_gemm8<<<dim3(8, V/256), 512, 0, stream>>>(hbf, temb, out, V, D);
}

// Round 16
// 1406.459 us; speedup vs baseline: 1.0335x; 1.0087x over previous
//
#include <hip/hip_runtime.h>
#include <hip/hip_bf16.h>
#include <math.h>

// ---------------- problem constants ----------------
#define B 2
#define S 1024
#define D 1024
#define H 16
#define DH 64
#define NL 6
#define GH 64
#define NP 16
#define V 32000
#define FF 2730
#define FFP 2752   // FF padded to multiple of 64
#define M (B*S)    // 2048 rows

typedef float fv4 __attribute__((ext_vector_type(4)));
typedef short bf16x8 __attribute__((ext_vector_type(8)));       // 8 bf16 = 4 VGPRs
typedef unsigned short us4 __attribute__((ext_vector_type(4))); // 4 bf16 = 8 bytes
typedef unsigned short us;

#define MFMA16 __builtin_amdgcn_mfma_f32_16x16x32_bf16
#define G2L16(g, l) __builtin_amdgcn_global_load_lds( \
    (const __attribute__((address_space(1))) void*)(g), \
    (__attribute__((address_space(3))) void*)(l), 16, 0, 0)

__device__ __forceinline__ us f2bf(float f) {
  union { float f; unsigned u; } v; v.f = f;
  unsigned r = v.u + 0x7FFFu + ((v.u >> 16) & 1u);   // RNE
  return (us)(r >> 16);
}
__device__ __forceinline__ float bf2f(us h) {
  union { unsigned u; float f; } v; v.u = ((unsigned)h) << 16;
  return v.f;
}

template<int N> __device__ __forceinline__ void waitcnt_vm() {
  if constexpr (N == 0)      asm volatile("s_waitcnt vmcnt(0)" ::: "memory");
  else if constexpr (N == 4) asm volatile("s_waitcnt vmcnt(4)" ::: "memory");
  else if constexpr (N == 8) asm volatile("s_waitcnt vmcnt(8)" ::: "memory");
  else if constexpr (N == 6) asm volatile("s_waitcnt vmcnt(6)" ::: "memory");
}

// m204 bijective XCD swizzle
__device__ __forceinline__ int xcd_remap(int flat, int nwg) {
  int q = nwg >> 3, r = nwg & 7;
  int xcd = flat & 7, idx = flat >> 3;
  return (xcd < r) ? (xcd * (q + 1) + idx) : (r * (q + 1) + (xcd - r) * q + idx);
}

// ======================================================================
// embed
// ======================================================================
__global__ __launch_bounds__(256) void k_embed(const int* __restrict__ ids,
                                               const float* __restrict__ emb,
                                               const float* __restrict__ winit,
                                               float* __restrict__ x) {
  int m = blockIdx.x, t = threadIdx.x;
  int id = ids[m];
  fv4 a = *(const fv4*)(emb + (size_t)id * D + 4*t);
  fv4 w = *(const fv4*)(winit + 4*t);
  *(fv4*)(x + (size_t)m * D + 4*t) = a + w;
}

// ======================================================================
// rope tables
// ======================================================================
__global__ void k_rope_tables(float* __restrict__ cosT, float* __restrict__ sinT) {
  int idx = blockIdx.x * blockDim.x + threadIdx.x;
  if (idx >= S * 32) return;
  int s = idx >> 5, f = idx & 31;
  float inv = powf(10000.0f, -2.0f * (float)f / (float)DH);
  float ang = (float)s * inv;
  cosT[idx] = cosf(ang);
  sinT[idx] = sinf(ang);
}

// ======================================================================
// Mp[h][d][e] -> bf16
// ======================================================================
__global__ __launch_bounds__(256) void k_mp(const float* __restrict__ pers,
                                            us* __restrict__ Mp) {
  int h = blockIdx.x, t = threadIdx.x;
  __shared__ float p[NP][DH];
  for (int i = t; i < NP * DH; i += 256) {
    int n = i / DH, dh = i % DH;
    p[n][dh] = pers[(size_t)n * D + h * DH + dh];
  }
  __syncthreads();
  for (int i = t; i < DH * DH; i += 256) {
    int d = i / DH, e = i % DH;
    float s = 0.f;
#pragma unroll
    for (int n = 0; n < NP; n++) s += p[n][d] * p[n][e];
    Mp[(size_t)h * DH * DH + i] = f2bf(s);
  }
}

// ======================================================================
// rmsnorm rows of D -> bf16 only
// ======================================================================
__global__ __launch_bounds__(256) void k_rms(const float* __restrict__ in,
                                             const float* __restrict__ w,
                                             us* __restrict__ outb) {
  int m = blockIdx.x, t = threadIdx.x;
  fv4 v = *(const fv4*)(in + (size_t)m * D + 4*t);
  float ss = v[0]*v[0] + v[1]*v[1] + v[2]*v[2] + v[3]*v[3];
#pragma unroll
  for (int off = 32; off > 0; off >>= 1) ss += __shfl_down(ss, off);
  __shared__ float buf[4];
  if ((t & 63) == 0) buf[t >> 6] = ss;
  __syncthreads();
  float tot = buf[0] + buf[1] + buf[2] + buf[3];
  float r = rsqrtf(tot * (1.0f / (float)D) + 1e-6f);
  fv4 wv = *(const fv4*)(w + 4*t);
  fv4 res = v * r * wv;
  us4 o; o[0]=f2bf(res[0]); o[1]=f2bf(res[1]); o[2]=f2bf(res[2]); o[3]=f2bf(res[3]);
  *(us4*)(outb + (size_t)m * D + 4*t) = o;
}

// ======================================================================
// FUSED rmsnorm + gamma gate (norm1 path), bf16 out only.
// ======================================================================
__global__ __launch_bounds__(256) void k_rmsg(const float* __restrict__ in,
                                              const float* __restrict__ w,
                                              const float* __restrict__ w1,
                                              const float* __restrict__ w2,
                                              us* __restrict__ outb,
                                              float* __restrict__ gko) {
  int m = blockIdx.x, t = threadIdx.x;
  __shared__ float hrow[D];
  __shared__ float buf[4];
  __shared__ float part[4][64];
  fv4 v = *(const fv4*)(in + (size_t)m * D + 4*t);
  float ss = v[0]*v[0] + v[1]*v[1] + v[2]*v[2] + v[3]*v[3];
#pragma unroll
  for (int off = 32; off > 0; off >>= 1) ss += __shfl_down(ss, off);
  if ((t & 63) == 0) buf[t >> 6] = ss;
  __syncthreads();
  float tot = buf[0] + buf[1] + buf[2] + buf[3];
  float r = rsqrtf(tot * (1.0f / (float)D) + 1e-6f);
  fv4 wv = *(const fv4*)(w + 4*t);
  fv4 res = v * r * wv;
  us4 o; o[0]=f2bf(res[0]); o[1]=f2bf(res[1]); o[2]=f2bf(res[2]); o[3]=f2bf(res[3]);
  *(us4*)(outb + (size_t)m * D + 4*t) = o;
  *(fv4*)&hrow[4*t] = res;
  __syncthreads();
  int oo = t & 63, seg = t >> 6;
  const float* wr = w1 + (size_t)oo * D + seg * 256;
  const float* hr = hrow + seg * 256;
  float acc = 0.f;
  for (int j = 0; j < 256; j += 4) {
    fv4 wv4 = *(const fv4*)(wr + j);
    acc += wv4[0]*hr[j] + wv4[1]*hr[j+1] + wv4[2]*hr[j+2] + wv4[3]*hr[j+3];
  }
  part[seg][oo] = acc;
  __syncthreads();
  if (t < 64) {
    float dot = part[0][t] + part[1][t] + part[2][t] + part[3][t];
    float sv = dot / (1.f + expf(-dot));
    float val = sv * w2[t];
#pragma unroll
    for (int off = 32; off > 0; off >>= 1) val += __shfl_down(val, off);
    if (t == 0) gko[m] = 1.f / (1.f + expf(-val));
  }
}

// ======================================================================
// flat f32 -> bf16 convert
// ======================================================================
__global__ __launch_bounds__(256) void k_cvt(const float* __restrict__ src,
                                             us* __restrict__ dst, int n) {
  for (size_t i = ((size_t)blockIdx.x * 256 + threadIdx.x) * 4; i < (size_t)n;
       i += (size_t)gridDim.x * 1024) {
    fv4 v = *(const fv4*)(src + i);
    us4 o; o[0]=f2bf(v[0]); o[1]=f2bf(v[1]); o[2]=f2bf(v[2]); o[3]=f2bf(v[3]);
    *(us4*)(dst + i) = o;
  }
}

// ======================================================================
// per-layer weight conversion, single launch
// ======================================================================
#define CVT_N1 786432   // 3*D*D/4
#define CVT_N2 262144   // D*D/4
#define CVT_N3 698880   // FF*D/4
#define CVT_N4 698880
#define CVT_N5 704512   // D * FFP/4
__global__ __launch_bounds__(256) void k_cvtw(const float* __restrict__ s1,
                                              const float* __restrict__ s2,
                                              const float* __restrict__ s3,
                                              const float* __restrict__ s4,
                                              const float* __restrict__ s5,
                                              us* __restrict__ d1, us* __restrict__ d2,
                                              us* __restrict__ d3, us* __restrict__ d4,
                                              us* __restrict__ d5) {
  const int TOT = CVT_N1 + CVT_N2 + CVT_N3 + CVT_N4 + CVT_N5;
  for (int i = blockIdx.x * 256 + threadIdx.x; i < TOT; i += gridDim.x * 256) {
    const float* s; us* d; int j = i;
    if (j < CVT_N1) { s = s1; d = d1; }
    else if ((j -= CVT_N1) < CVT_N2) { s = s2; d = d2; }
    else if ((j -= CVT_N2) < CVT_N3) { s = s3; d = d3; }
    else if ((j -= CVT_N3) < CVT_N4) { s = s4; d = d4; }
    else {
      j -= CVT_N4;
      int r = j / (FFP/4), c = (j % (FFP/4)) * 4;
      us4 o;
#pragma unroll
      for (int q = 0; q < 4; q++) {
        int cc = c + q;
        o[q] = (cc < FF) ? f2bf(s5[(size_t)r * FF + cc]) : (us)0;
      }
      *(us4*)&d5[(size_t)r * FFP + c] = o;
      continue;
    }
    fv4 v = *(const fv4*)(s + (size_t)4 * j);
    us4 o; o[0]=f2bf(v[0]); o[1]=f2bf(v[1]); o[2]=f2bf(v[2]); o[3]=f2bf(v[3]);
    *(us4*)&d[(size_t)4 * j] = o;
  }
}

// ======================================================================
// PIPELINED bf16 MFMA GEMM (g8 discipline).
// ======================================================================
template<int ACW, int BCW>
__device__ __forceinline__ void pg_stage(const us* __restrict__ A,
                                         const us* __restrict__ W,
                                         us* bufA, us* bufB,
                                         int m0, int n0, int Nn, int Kk,
                                         int tile, int w, int lane, int lr, int sx) {
#pragma unroll
  for (int i = 0; i < ACW; i++) {
    int chunk = w * ACW + i;
    G2L16(A + (size_t)(m0 + chunk*8 + lr) * Kk + tile*64 + sx, bufA + chunk*512 + lane*8);
  }
#pragma unroll
  for (int i = 0; i < BCW; i++) {
    int chunk = w * BCW + i;
    int wrow = n0 + chunk*8 + lr;
    if (wrow >= Nn) wrow = Nn - 1;
    G2L16(W + (size_t)wrow * Kk + tile*64 + sx, bufB + chunk*512 + lane*8);
  }
}

template<int EPI, int BM, int BN>
__global__ __launch_bounds__(256) void k_pgemm(const us* __restrict__ A,
                                               const us* __restrict__ W,
                                               float* __restrict__ C,
                                               int Nn, int Kk) {
  constexpr int FM = BM / 32, FN = BN / 32;
  constexpr int ACW = BM / 32, BCW = BN / 32;
  constexpr int L = ACW + BCW;
  __shared__ __attribute__((aligned(16))) us lds[2][(BM + BN) * 64];
  int t = threadIdx.x, lane = t & 63, w = t >> 6;
  int l16 = lane & 15, lkb = lane >> 4, lr = lane >> 3;
  int sx = ((lane & 7) ^ lr) * 8;
  int sw = l16 & 7;
  int gx = gridDim.x, nwg = gx * gridDim.y;
  int nf = xcd_remap(blockIdx.y * gx + blockIdx.x, nwg);
  int m0 = (nf % gx) * BM, n0 = (nf / gx) * BN;
  int wr = w >> 1, wc = w & 1;
  int NK = Kk >> 6;

  pg_stage<ACW,BCW>(A, W, lds[0], lds[0] + BM*64, m0, n0, Nn, Kk, 0, w, lane, lr, sx);
  pg_stage<ACW,BCW>(A, W, lds[1], lds[1] + BM*64, m0, n0, Nn, Kk, 1, w, lane, lr, sx);

  fv4 acc[FM][FN] = {};
  for (int T = 0; T < NK; T++) {
    if (T == NK - 1) waitcnt_vm<0>(); else waitcnt_vm<L>();
    __builtin_amdgcn_s_barrier();
    const us* bufA = lds[T & 1];
    const us* bufB = bufA + BM*64;
    bf16x8 af[2][FM], bfh[2][FN];
#pragma unroll
    for (int kk = 0; kk < 2; kk++) {
#pragma unroll
      for (int i = 0; i < FM; i++)
        af[kk][i] = *(const bf16x8*)&bufA[(wr*(BM/2) + i*16 + l16)*64 + (((kk*4+lkb)) ^ sw)*8];
#pragma unroll
      for (int j = 0; j < FN; j++)
        bfh[kk][j] = *(const bf16x8*)&bufB[(wc*(BN/2) + j*16 + l16)*64 + (((kk*4+lkb)) ^ sw)*8];
    }
    __builtin_amdgcn_s_barrier();
    if (T + 2 < NK)
      pg_stage<ACW,BCW>(A, W, lds[T & 1], lds[T & 1] + BM*64, m0, n0, Nn, Kk, T + 2, w, lane, lr, sx);
    __builtin_amdgcn_s_setprio(1);
#pragma unroll
    for (int kk = 0; kk < 2; kk++)
#pragma unroll
      for (int i = 0; i < FM; i++)
#pragma unroll
        for (int j = 0; j < FN; j++)
          acc[i][j] = MFMA16(af[kk][i], bfh[kk][j], acc[i][j], 0, 0, 0);
    __builtin_amdgcn_s_setprio(0);
  }

#pragma unroll
  for (int i = 0; i < FM; i++) {
    int gr0 = m0 + wr*(BM/2) + i*16 + lkb*4;
#pragma unroll
    for (int j = 0; j < FN; j++) {
      int gc = n0 + wc*(BN/2) + j*16 + l16;
      if (gc < Nn) {
#pragma unroll
        for (int r = 0; r < 4; r++) {
          size_t idx = (size_t)(gr0 + r) * Nn + gc;
          float val = acc[i][j][r];
          if (EPI == 0) C[idx] = val;
          else C[idx] += val;
        }
      }
    }
  }
}

// ======================================================================
// PIPELINED fused FFN w1/w2 GEMM (dual-B), 128x64, L=8.
// ======================================================================
__device__ __forceinline__ void pf_stage(const us* __restrict__ A,
                                         const us* __restrict__ W1,
                                         const us* __restrict__ W2,
                                         us* buf, int m0, int n0, int Nn, int Kk,
                                         int tile, int w, int lane, int lr, int sx) {
#pragma unroll
  for (int i = 0; i < 4; i++) {
    int chunk = w * 4 + i;
    G2L16(A + (size_t)(m0 + chunk*8 + lr) * Kk + tile*64 + sx, buf + chunk*512 + lane*8);
  }
#pragma unroll
  for (int i = 0; i < 2; i++) {
    int chunk = w * 2 + i;
    int wrow = n0 + chunk*8 + lr;
    if (wrow >= Nn) wrow = Nn - 1;
    G2L16(W1 + (size_t)wrow * Kk + tile*64 + sx, buf + 8192 + chunk*512 + lane*8);
    G2L16(W2 + (size_t)wrow * Kk + tile*64 + sx, buf + 12288 + chunk*512 + lane*8);
  }
}

__global__ __launch_bounds__(256) void k_pffn12(const us* __restrict__ A,
                                                const us* __restrict__ W1,
                                                const us* __restrict__ W2,
                                                us* __restrict__ Cb,
                                                int Nn, int Kk) {
  __shared__ __attribute__((aligned(16))) us lds[2][16384];
  int t = threadIdx.x, lane = t & 63, w = t >> 6;
  int l16 = lane & 15, lkb = lane >> 4, lr = lane >> 3;
  int sx = ((lane & 7) ^ lr) * 8;
  int sw = l16 & 7;
  int gx = gridDim.x, nwg = gx * gridDim.y;
  int nf = xcd_remap(blockIdx.y * gx + blockIdx.x, nwg);
  int m0 = (nf % gx) * 128, n0 = (nf / gx) * 64;
  int wr = w >> 1, wc = w & 1;
  int NK = Kk >> 6;

  pf_stage(A, W1, W2, lds[0], m0, n0, Nn, Kk, 0, w, lane, lr, sx);
  pf_stage(A, W1, W2, lds[1], m0, n0, Nn, Kk, 1, w, lane, lr, sx);

  fv4 acc1[4][2] = {}, acc2[4][2] = {};
  for (int T = 0; T < NK; T++) {
    if (T == NK - 1) waitcnt_vm<0>(); else waitcnt_vm<8>();
    __builtin_amdgcn_s_barrier();
    const us* buf = lds[T & 1];
    bf16x8 af[2][4], b1f[2][2], b2f[2][2];
#pragma unroll
    for (int kk = 0; kk < 2; kk++) {
#pragma unroll
      for (int i = 0; i < 4; i++)
        af[kk][i] = *(const bf16x8*)&buf[(wr*64 + i*16 + l16)*64 + ((kk*4+lkb) ^ sw)*8];
#pragma unroll
      for (int j = 0; j < 2; j++) {
        b1f[kk][j] = *(const bf16x8*)&buf[8192  + (wc*32 + j*16 + l16)*64 + ((kk*4+lkb) ^ sw)*8];
        b2f[kk][j] = *(const bf16x8*)&buf[12288 + (wc*32 + j*16 + l16)*64 + ((kk*4+lkb) ^ sw)*8];
      }
    }
    __builtin_amdgcn_s_barrier();
    if (T + 2 < NK)
      pf_stage(A, W1, W2, lds[T & 1], m0, n0, Nn, Kk, T + 2, w, lane, lr, sx);
    __builtin_amdgcn_s_setprio(1);
#pragma unroll
    for (int kk = 0; kk < 2; kk++)
#pragma unroll
      for (int i = 0; i < 4; i++)
#pragma unroll
        for (int j = 0; j < 2; j++) {
          acc1[i][j] = MFMA16(af[kk][i], b1f[kk][j], acc1[i][j], 0, 0, 0);
          acc2[i][j] = MFMA16(af[kk][i], b2f[kk][j], acc2[i][j], 0, 0, 0);
        }
    __builtin_amdgcn_s_setprio(0);
  }

#pragma unroll
  for (int i = 0; i < 4; i++) {
    int gr0 = m0 + wr*64 + i*16 + lkb*4;
#pragma unroll
    for (int j = 0; j < 2; j++) {
      int gc = n0 + wc*32 + j*16 + l16;
      if (gc < Nn) {
#pragma unroll
        for (int r = 0; r < 4; r++) {
          float v1 = acc1[i][j][r], v2 = acc2[i][j][r];
          float sv = v1 / (1.f + expf(-v1));
          Cb[(size_t)(gr0 + r) * FFP + gc] = f2bf(sv * v2);
        }
      }
    }
  }
}

// ======================================================================
// PIPELINED qkv GEMM + head-split + qk-rmsnorm + rope epilogue.
// ======================================================================
__global__ __launch_bounds__(256) void k_pqkv(const us* __restrict__ A,
                                              const us* __restrict__ W,
                                              const float* __restrict__ qnw,
                                              const float* __restrict__ knw,
                                              const float* __restrict__ cosT,
                                              const float* __restrict__ sinT,
                                              us* __restrict__ qb,
                                              us* __restrict__ kb,
                                              us* __restrict__ vb) {
  const int Kk = D, Nn = 3 * D;
  __shared__ __attribute__((aligned(16))) us lds[2][16384];
  int t = threadIdx.x, lane = t & 63, w = t >> 6;
  int l16 = lane & 15, lkb = lane >> 4, lr = lane >> 3;
  int sx = ((lane & 7) ^ lr) * 8;
  int sw = l16 & 7;
  int gx = gridDim.x, nwg = gx * gridDim.y;
  int nf = xcd_remap(blockIdx.y * gx + blockIdx.x, nwg);
  int m0 = (nf % gx) * 128, n0 = (nf / gx) * 128;
  int wr = w >> 1, wc = w & 1;
  int NK = Kk >> 6;

  pg_stage<4,4>(A, W, lds[0], lds[0] + 8192, m0, n0, Nn, Kk, 0, w, lane, lr, sx);
  pg_stage<4,4>(A, W, lds[1], lds[1] + 8192, m0, n0, Nn, Kk, 1, w, lane, lr, sx);

  fv4 acc[4][4] = {};
  for (int T = 0; T < NK; T++) {
    if (T == NK - 1) waitcnt_vm<0>(); else waitcnt_vm<8>();
    __builtin_amdgcn_s_barrier();
    const us* bufA = lds[T & 1];
    const us* bufB = bufA + 8192;
    bf16x8 af[2][4], bfh[2][4];
#pragma unroll
    for (int kk = 0; kk < 2; kk++) {
#pragma unroll
      for (int i = 0; i < 4; i++) {
        af[kk][i]  = *(const bf16x8*)&bufA[(wr*64 + i*16 + l16)*64 + ((kk*4+lkb) ^ sw)*8];
        bfh[kk][i] = *(const bf16x8*)&bufB[(wc*64 + i*16 + l16)*64 + ((kk*4+lkb) ^ sw)*8];
      }
    }
    __builtin_amdgcn_s_barrier();
    if (T + 2 < NK)
      pg_stage<4,4>(A, W, lds[T & 1], lds[T & 1] + 8192, m0, n0, Nn, Kk, T + 2, w, lane, lr, sx);
    __builtin_amdgcn_s_setprio(1);
#pragma unroll
    for (int kk = 0; kk < 2; kk++)
#pragma unroll
      for (int i = 0; i < 4; i++)
#pragma unroll
        for (int j = 0; j < 4; j++)
          acc[i][j] = MFMA16(af[kk][i], bfh[kk][j], acc[i][j], 0, 0, 0);
    __builtin_amdgcn_s_setprio(0);
  }

  // ---- fused epilogue ----
  int part = n0 >> 10;
  int hd = ((n0 & 1023) + wc * 64) >> 6;
  us* dst = (part == 0) ? qb : ((part == 1) ? kb : vb);
  if (part == 2) {
#pragma unroll
    for (int i = 0; i < 4; i++)
#pragma unroll
      for (int r = 0; r < 4; r++) {
        int m = m0 + wr*64 + i*16 + lkb*4 + r;
        int b = m >> 10, s = m & 1023;
        us* drow = dst + (((size_t)(b*H + hd)) * S + s) * 64;
#pragma unroll
        for (int j = 0; j < 4; j++) drow[j*16 + l16] = f2bf(acc[i][j][r]);
      }
  } else {
    const float* nw = (part == 0) ? qnw : knw;
    float w0 = nw[l16], w1 = nw[16 + l16], w2 = nw[32 + l16], w3 = nw[48 + l16];
#pragma unroll
    for (int i = 0; i < 4; i++)
#pragma unroll
      for (int r = 0; r < 4; r++) {
        int m = m0 + wr*64 + i*16 + lkb*4 + r;
        int b = m >> 10, s = m & 1023;
        float a0 = acc[i][0][r], a1 = acc[i][1][r], a2 = acc[i][2][r], a3 = acc[i][3][r];
        float s2 = a0*a0 + a1*a1 + a2*a2 + a3*a3;
        s2 += __shfl_xor(s2, 1); s2 += __shfl_xor(s2, 2);
        s2 += __shfl_xor(s2, 4); s2 += __shfl_xor(s2, 8);
        float rs = rsqrtf(s2 * (1.0f / (float)DH) + 1e-6f);
        float v0 = a0 * rs * w0, v1 = a1 * rs * w1, v2 = a2 * rs * w2, v3 = a3 * rs * w3;
        float c0 = cosT[s*32 + l16],      sn0 = sinT[s*32 + l16];
        float c1 = cosT[s*32 + 16 + l16], sn1 = sinT[s*32 + 16 + l16];
        us* drow = dst + (((size_t)(b*H + hd)) * S + s) * 64;
        drow[l16]      = f2bf(v0 * c0 - v2 * sn0);
        drow[16 + l16] = f2bf(v1 * c1 - v3 * sn1);
        drow[32 + l16] = f2bf(v2 * c0 + v0 * sn0);
        drow[48 + l16] = f2bf(v3 * c1 + v1 * sn1);
      }
  }
}

// ======================================================================
// 256x256 8-wave bf16 GEMM — lm_head. FINE-PHASE variant: per tile,
// 4 quadrant phases {8 ds_reads; stage-issue (phases 0-1); 16 MFMA}.
// Race-free: tile T+1 staged into buf (T+1)&1, whose previous tile's
// reads completed before this tile's boundary barrier. vmcnt(0)+barrier
// at tile boundary (loads issued >=2.5 phases earlier). Accumulation
// order per acc element unchanged (kk0 then kk1) -> bit-identical.
// ======================================================================
struct G8 { const us* A; const us* W; int K; int m0; int n0; };

__device__ __forceinline__ void g8_issue(const G8& g, us* lds8, int q, int t) {
  int tile = q >> 2, h = q & 3;
  us* buf = lds8 + (size_t)(tile & 1) * 32768;
  const us* Gp = (h < 2) ? g.A : g.W;
  int rbase = ((h < 2) ? g.m0 : g.n0) + (h & 1) * 128;
  us* part = buf + (h >> 1) * 16384 + (h & 1) * 8192;
  int r8 = t >> 3;
  int sl = (((t & 7) ^ (r8 & 7)) * 8);
#pragma unroll
  for (int c = 0; c < 2; c++) {
    const us* src = Gp + (size_t)(rbase + c * 64 + r8) * g.K + tile * 64 + sl;
    us* dst = part + c * 4096 + t * 8;
    G2L16(src, dst);
  }
}

__global__ __launch_bounds__(512, 2) void k_gemm8(const us* __restrict__ A,
                                                  const us* __restrict__ W,
                                                  float* __restrict__ C,
                                                  int Nn, int Kk) {
  __shared__ __attribute__((aligned(16))) us lds8[65536];
  int t = threadIdx.x, lane = t & 63, w = t >> 6;
  int wm = w >> 2, wn = w & 3;
  int l16 = lane & 15, lkb = lane >> 4;
  int gx = gridDim.x, nwg = gx * gridDim.y;
  int nf = xcd_remap(blockIdx.y * gx + blockIdx.x, nwg);
  int m0 = (nf % gx) * 256, n0 = (nf / gx) * 256;
  G8 g{A, W, Kk, m0, n0};
  int NK = Kk >> 6;

  // prologue: tile 0 fully staged
#pragma unroll
  for (int q = 0; q < 4; ++q) g8_issue(g, lds8, q, t);

  fv4 acc[8][4] = {};
  int arow = wm * 128 + l16;
  int brow = wn * 64 + l16;
  int sw = l16 & 7;

  for (int T = 0; T < NK; ++T) {
    waitcnt_vm<0>();                       // own tile-T loads landed
    __builtin_amdgcn_s_barrier();          // all waves' loads landed
    const us* buf = lds8 + (size_t)(T & 1) * 32768;
    bool pf = (T + 1 < NK);
    int qb = (T + 1) * 4;
    bf16x8 a[4], bfr[4];

    // ---- phase 0: b(kk0) + a(rows 0-3, kk0); issue 2 ht; MFMA ----
#pragma unroll
    for (int j = 0; j < 4; j++)
      bfr[j] = *(const bf16x8*)&buf[16384 + (brow + j*16)*64 + ((lkb    ) ^ sw)*8];
#pragma unroll
    for (int i = 0; i < 4; i++)
      a[i] = *(const bf16x8*)&buf[(arow + i*16)*64 + ((lkb    ) ^ sw)*8];
    if (pf) { g8_issue(g, lds8, qb + 0, t); g8_issue(g, lds8, qb + 1, t); }
    __builtin_amdgcn_s_setprio(1);
#pragma unroll
    for (int i = 0; i < 4; i++)
#pragma unroll
      for (int j = 0; j < 4; j++)
        acc[i][j] = MFMA16(a[i], bfr[j], acc[i][j], 0, 0, 0);
    __builtin_amdgcn_s_setprio(0);

    // ---- phase 1: a(rows 4-7, kk0); issue 2 ht; MFMA ----
#pragma unroll
    for (int i = 0; i < 4; i++)
      a[i] = *(const bf16x8*)&buf[(arow + (i+4)*16)*64 + ((lkb    ) ^ sw)*8];
    if (pf) { g8_issue(g, lds8, qb + 2, t); g8_issue(g, lds8, qb + 3, t); }
    __builtin_amdgcn_s_setprio(1);
#pragma unroll
    for (int i = 0; i < 4; i++)
#pragma unroll
      for (int j = 0; j < 4; j++)
        acc[i+4][j] = MFMA16(a[i], bfr[j], acc[i+4][j], 0, 0, 0);
    __builtin_amdgcn_s_setprio(0);

    // ---- phase 2: b(kk1) + a(rows 0-3, kk1); MFMA ----
#pragma unroll
    for (int j = 0; j < 4; j++)
      bfr[j] = *(const bf16x8*)&buf[16384 + (brow + j*16)*64 + ((lkb + 4) ^ sw)*8];
#pragma unroll
    for (int i = 0; i < 4; i++)
      a[i] = *(const bf16x8*)&buf[(arow + i*16)*64 + ((lkb + 4) ^ sw)*8];
    __builtin_amdgcn_s_setprio(1);
#pragma unroll
    for (int i = 0; i < 4; i++)
#pragma unroll
      for (int j = 0; j < 4; j++)
        acc[i][j] = MFMA16(a[i], bfr[j], acc[i][j], 0, 0, 0);
    __builtin_amdgcn_s_setprio(0);

    // ---- phase 3: a(rows 4-7, kk1); MFMA ----
#pragma unroll
    for (int i = 0; i < 4; i++)
      a[i] = *(const bf16x8*)&buf[(arow + (i+4)*16)*64 + ((lkb + 4) ^ sw)*8];
    __builtin_amdgcn_s_setprio(1);
#pragma unroll
    for (int i = 0; i < 4; i++)
#pragma unroll
      for (int j = 0; j < 4; j++)
        acc[i+4][j] = MFMA16(a[i], bfr[j], acc[i+4][j], 0, 0, 0);
    __builtin_amdgcn_s_setprio(0);
  }

#pragma unroll
  for (int i = 0; i < 8; i++) {
    int gr0 = m0 + wm*128 + i*16 + lkb*4;
#pragma unroll
    for (int j = 0; j < 4; j++) {
      int gc = n0 + wn*64 + j*16 + l16;
#pragma unroll
      for (int r = 0; r < 4; r++)
        C[(size_t)(gr0 + r) * Nn + gc] = acc[i][j][r];
    }
  }
}

// ======================================================================
// 64x64 bf16 transpose: (bh, s, dh) -> (bh, dh, s); grid.z selects k or v
// ======================================================================
__global__ __launch_bounds__(256) void k_tr2(const us* __restrict__ ksrc,
                                             const us* __restrict__ vsrc,
                                             us* __restrict__ kdst,
                                             us* __restrict__ vdst) {
  __shared__ __attribute__((aligned(16))) us tile[64*72];
  int st = blockIdx.x, bh = blockIdx.y, t = threadIdx.x;
  const us* src = blockIdx.z ? vsrc : ksrc;
  us* dst = blockIdx.z ? vdst : kdst;
  const us* sp = src + ((size_t)bh * S + st*64) * 64;
#pragma unroll
  for (int p = 0; p < 2; p++) {
    int idx = t + p*256;
    int r = idx >> 3, c = (idx & 7)*8;
    *(bf16x8*)&tile[r*72 + c] = *(const bf16x8*)&sp[(size_t)idx*8];
  }
  __syncthreads();
  int d = t >> 2;
#pragma unroll
  for (int cc = 0; cc < 16; cc += 8) {
    int s0 = (t & 3)*16 + cc;
    bf16x8 vv;
#pragma unroll
    for (int j2 = 0; j2 < 8; j2++) vv[j2] = (short)tile[(s0+j2)*72 + d];
    *(bf16x8*)&dst[((size_t)bh*64 + d)*S + st*64 + s0] = vv;
  }
}

// ======================================================================
// FUSED omega-memory + flash attention — pipelined staging + IN-BLOCK
// gk prefix scan.
// ======================================================================
#define SM_OFF 24.0f

__device__ __forceinline__ void m_stage(const us* __restrict__ src, int rstride,
                                        us* buf, int w, int lane, int lr, int sx8) {
#pragma unroll
  for (int i = 0; i < 2; i++) {
    int rbase = i * 32 + w * 8;
    G2L16(src + (size_t)(rbase + lr) * rstride + sx8, buf + rbase * 64 + lane * 8);
  }
}

__global__ __launch_bounds__(256) void k_matt(const us* __restrict__ qb,
                                              const us* __restrict__ kb,
                                              const us* __restrict__ kbT,
                                              const us* __restrict__ vbT,
                                              const us* __restrict__ MpB,
                                              const float* __restrict__ gk,
                                              const float* __restrict__ mg, int layer,
                                              us* __restrict__ ob) {
  int nf = xcd_remap(blockIdx.y * 8 + blockIdx.x, 256);
  int xx = nf & 7, bh = nf >> 3;
  int b = bh >> 4, hh = bh & 15;
  int t = threadIdx.x, lane = t & 63, w = t >> 6;
  int l16 = lane & 15, lg = lane >> 4, lr = lane >> 3;
  int sx8 = ((lane & 7) ^ lr) * 8;
  int sw = l16 & 7;

  __shared__ __attribute__((aligned(16))) us Qs[64*72];
  __shared__ __attribute__((aligned(16))) us Ms[64*72];
  __shared__ __attribute__((aligned(16))) us Ps[64*72];
  __shared__ __attribute__((aligned(16))) us KT[2][2][64*64];
  __shared__ float gkL[S], nrmL[S];
  __shared__ float wsum2[4];

  float gate = 1.f / (1.f + expf(-mg[layer]));
  const us* kbB = kb + (size_t)bh * S * 64;
  const us* ktB = kbT + (size_t)bh * 64 * S;
  const us* vtB = vbT + (size_t)bh * 64 * S;

  // ---- once per block: Mp, gk row, and in-block prefix scan ----
  {
    const us* mp = MpB + (size_t)hh * 4096;
#pragma unroll
    for (int p = 0; p < 2; p++) {
      int idx = t + p*256;
      int r = idx >> 3, c = (idx & 7) * 8;
      *(bf16x8*)&Ms[r*72 + c] = *(const bf16x8*)&mp[(size_t)idx*8];
    }
#pragma unroll
    for (int p = 0; p < 4; p++) gkL[t + p*256] = gk[b*S + t + p*256];
  }
  __syncthreads();
  {
    float v0 = gkL[4*t], v1 = gkL[4*t+1], v2 = gkL[4*t+2], v3 = gkL[4*t+3];
    float r0 = v0, r1 = r0 + v1, r2 = r1 + v2, r3 = r2 + v3;
    float s = r3;
#pragma unroll
    for (int off = 1; off < 64; off <<= 1) {
      float y = __shfl_up(s, off, 64);
      if (lane >= off) s += y;
    }
    if (lane == 63) wsum2[w] = s;
    __syncthreads();
    float wexcl = 0.f;
    if (w == 1) wexcl = wsum2[0];
    else if (w == 2) wexcl = wsum2[0] + wsum2[1];
    else if (w == 3) wexcl = wsum2[0] + wsum2[1] + wsum2[2];
    float base = wexcl + (s - r3);
    nrmL[4*t]   = (float)NP + base + r0;
    nrmL[4*t+1] = (float)NP + base + r1;
    nrmL[4*t+2] = (float)NP + base + r2;
    nrmL[4*t+3] = (float)NP + base + r3;
  }

  for (int sel = 0; sel < 2; sel++) {
    int qt = sel ? (15 - xx) : xx;
    __syncthreads();
    {
      const us* src = qb + ((size_t)bh * S + qt*64) * 64;
#pragma unroll
      for (int p = 0; p < 2; p++) {
        int idx = t + p*256;
        int r = idx >> 3, c = (idx & 7) * 8;
        *(bf16x8*)&Qs[r*72 + c] = *(const bf16x8*)&src[(size_t)idx*8];
      }
    }
    __syncthreads();

    bf16x8 aq0 = *(const bf16x8*)&Qs[(16*w + l16)*72 + lg*8];
    bf16x8 aq1 = *(const bf16x8*)&Qs[(16*w + l16)*72 + 32 + lg*8];

    fv4 am[4];
#pragma unroll
    for (int j = 0; j < 4; j++) {
      bf16x8 b0 = *(const bf16x8*)&Ms[(16*j + l16)*72 + lg*8];
      bf16x8 b1 = *(const bf16x8*)&Ms[(16*j + l16)*72 + 32 + lg*8];
      fv4 z = {};
      z = MFMA16(aq0, b0, z, 0, 0, 0);
      z = MFMA16(aq1, b1, z, 0, 0, 0);
      am[j] = z;
    }

    // ======== phase 1: omega memory (pipelined K + K^T) ========
    m_stage(kbB,            64, KT[0][0], w, lane, lr, sx8);
    m_stage(ktB,            S,  KT[0][1], w, lane, lr, sx8);
    m_stage(kbB + 4096,     64, KT[1][0], w, lane, lr, sx8);
    m_stage(ktB + 64,       S,  KT[1][1], w, lane, lr, sx8);
    for (int kt = 0; kt <= qt; kt++) {
      int ks = kt * 64;
      if (kt == qt) waitcnt_vm<0>(); else waitcnt_vm<4>();
      __builtin_amdgcn_s_barrier();
      const us* bK = KT[kt & 1][0];
      const us* bT = KT[kt & 1][1];
      bf16x8 kf0[4], kf1[4], tf0[4], tf1[4];
      float gv[4];
#pragma unroll
      for (int j = 0; j < 4; j++) {
        int row = 16*j + l16;
        kf0[j] = *(const bf16x8*)&bK[row*64 + ((lg    ) ^ sw)*8];
        kf1[j] = *(const bf16x8*)&bK[row*64 + ((lg + 4) ^ sw)*8];
        tf0[j] = *(const bf16x8*)&bT[row*64 + ((lg    ) ^ sw)*8];
        tf1[j] = *(const bf16x8*)&bT[row*64 + ((lg + 4) ^ sw)*8];
        gv[j] = gkL[ks + row];
      }
      __builtin_amdgcn_s_barrier();
      if (kt + 2 <= qt) {
        m_stage(kbB + (size_t)(kt+2)*4096, 64, KT[kt & 1][0], w, lane, lr, sx8);
        m_stage(ktB + (kt+2)*64,           S,  KT[kt & 1][1], w, lane, lr, sx8);
      }
      fv4 sc[4];
      __builtin_amdgcn_s_setprio(1);
#pragma unroll
      for (int j = 0; j < 4; j++) {
        fv4 z = {};
        z = MFMA16(aq0, kf0[j], z, 0, 0, 0);
        z = MFMA16(aq1, kf1[j], z, 0, 0, 0);
        sc[j] = z;
      }
      __builtin_amdgcn_s_setprio(0);
      if (kt < qt) {
#pragma unroll
        for (int j = 0; j < 4; j++)
#pragma unroll
          for (int r = 0; r < 4; r++)
            Ps[(16*w + lg*4 + r)*72 + 16*j + l16] = f2bf(sc[j][r] * gv[j]);
      } else {
#pragma unroll
        for (int j = 0; j < 4; j++) {
          int kj = 16*j + l16;
#pragma unroll
          for (int r = 0; r < 4; r++) {
            int qi = 16*w + lg*4 + r;
            Ps[qi*72 + kj] = (kj > qi) ? (us)0 : f2bf(sc[j][r] * gv[j]);
          }
        }
      }
      bf16x8 ap0 = *(const bf16x8*)&Ps[(16*w + l16)*72 + lg*8];
      bf16x8 ap1 = *(const bf16x8*)&Ps[(16*w + l16)*72 + 32 + lg*8];
      __builtin_amdgcn_s_setprio(1);
#pragma unroll
      for (int j = 0; j < 4; j++) {
        am[j] = MFMA16(ap0, tf0[j], am[j], 0, 0, 0);
        am[j] = MFMA16(ap1, tf1[j], am[j], 0, 0, 0);
      }
      __builtin_amdgcn_s_setprio(0);
    }

    // q' update: Qs rows wave-private -> no barriers
#pragma unroll
    for (int j = 0; j < 4; j++)
#pragma unroll
      for (int r = 0; r < 4; r++) {
        int qi = 16*w + lg*4 + r, dj = 16*j + l16;
        float qold = bf2f(Qs[qi*72 + dj]);
        float qn = (1.f - gate) * qold + gate * (am[j][r] / nrmL[qt*64 + qi]);
        Qs[qi*72 + dj] = f2bf(qn);
      }
    aq0 = *(const bf16x8*)&Qs[(16*w + l16)*72 + lg*8];
    aq1 = *(const bf16x8*)&Qs[(16*w + l16)*72 + 32 + lg*8];

    // ======== phase 2: flash attention (pipelined K + V^T) ========
    float lsum[4] = {};
    fv4 ao[4] = {};
    m_stage(kbB,            64, KT[0][0], w, lane, lr, sx8);
    m_stage(vtB,            S,  KT[0][1], w, lane, lr, sx8);
    m_stage(kbB + 4096,     64, KT[1][0], w, lane, lr, sx8);
    m_stage(vtB + 64,       S,  KT[1][1], w, lane, lr, sx8);
    for (int kt = 0; kt <= qt; kt++) {
      if (kt == qt) waitcnt_vm<0>(); else waitcnt_vm<4>();
      __builtin_amdgcn_s_barrier();
      const us* bK = KT[kt & 1][0];
      const us* bV = KT[kt & 1][1];
      bf16x8 kf0[4], kf1[4], vf0[4], vf1[4];
#pragma unroll
      for (int j = 0; j < 4; j++) {
        int row = 16*j + l16;
        kf0[j] = *(const bf16x8*)&bK[row*64 + ((lg    ) ^ sw)*8];
        kf1[j] = *(const bf16x8*)&bK[row*64 + ((lg + 4) ^ sw)*8];
        vf0[j] = *(const bf16x8*)&bV[row*64 + ((lg    ) ^ sw)*8];
        vf1[j] = *(const bf16x8*)&bV[row*64 + ((lg + 4) ^ sw)*8];
      }
      __builtin_amdgcn_s_barrier();
      if (kt + 2 <= qt) {
        m_stage(kbB + (size_t)(kt+2)*4096, 64, KT[kt & 1][0], w, lane, lr, sx8);
        m_stage(vtB + (kt+2)*64,           S,  KT[kt & 1][1], w, lane, lr, sx8);
      }
      fv4 sc[4];
      __builtin_amdgcn_s_setprio(1);
#pragma unroll
      for (int j = 0; j < 4; j++) {
        fv4 z = {};
        z = MFMA16(aq0, kf0[j], z, 0, 0, 0);
        z = MFMA16(aq1, kf1[j], z, 0, 0, 0);
        sc[j] = z;
      }
      __builtin_amdgcn_s_setprio(0);
      if (kt < qt) {
#pragma unroll
        for (int j = 0; j < 4; j++)
#pragma unroll
          for (int r = 0; r < 4; r++) {
            float p = __expf(fmaf(sc[j][r], 0.125f, -SM_OFF));
            lsum[r] += p;
            Ps[(16*w + lg*4 + r)*72 + 16*j + l16] = f2bf(p);
          }
      } else {
#pragma unroll
        for (int j = 0; j < 4; j++) {
          int kj = 16*j + l16;
#pragma unroll
          for (int r = 0; r < 4; r++) {
            int qi = 16*w + lg*4 + r;
            float p = (kj > qi) ? 0.f : __expf(fmaf(sc[j][r], 0.125f, -SM_OFF));
            lsum[r] += p;
            Ps[qi*72 + kj] = f2bf(p);
          }
        }
      }
      bf16x8 ap0 = *(const bf16x8*)&Ps[(16*w + l16)*72 + lg*8];
      bf16x8 ap1 = *(const bf16x8*)&Ps[(16*w + l16)*72 + 32 + lg*8];
      __builtin_amdgcn_s_setprio(1);
#pragma unroll
      for (int j = 0; j < 4; j++) {
        ao[j] = MFMA16(ap0, vf0[j], ao[j], 0, 0, 0);
        ao[j] = MFMA16(ap1, vf1[j], ao[j], 0, 0, 0);
      }
      __builtin_amdgcn_s_setprio(0);
    }

#pragma unroll
    for (int r = 0; r < 4; r++) {
      float l = lsum[r];
      l += __shfl_xor(l, 1);
      l += __shfl_xor(l, 2);
      l += __shfl_xor(l, 4);
      l += __shfl_xor(l, 8);
      lsum[r] = l;
    }
#pragma unroll
    for (int j = 0; j < 4; j++)
#pragma unroll
      for (int r = 0; r < 4; r++) {
        int qi = 16*w + lg*4 + r;
        ob[((size_t)b*S + qt*64 + qi) * D + hh*64 + 16*j + l16] = f2bf(ao[j][r] / lsum[r]);
      }
  }
}

// ======================================================================
// launcher
// ======================================================================
extern "C" void kernel_launch(void* const* d_in, const int* in_sizes, int n_in,
                              void* d_out, int out_size, void* d_ws, size_t ws_size,
                              hipStream_t stream) {
  const int*   ids      = (const int*)d_in[0];
  const float* tok_emb  = (const float*)d_in[1];
  const float* w_init   = (const float*)d_in[2];
  const float* persist  = (const float*)d_in[3];
  const float* norm1_w  = (const float*)d_in[4];
  const float* norm2_w  = (const float*)d_in[5];
  const float* norm_f_w = (const float*)d_in[6];
  const float* qkv_w    = (const float*)d_in[7];
  const float* q_norm_w = (const float*)d_in[8];
  const float* k_norm_w = (const float*)d_in[9];
  const float* gamma_w1 = (const float*)d_in[10];
  const float* gamma_w2 = (const float*)d_in[11];
  const float* mem_gate = (const float*)d_in[12];
  const float* w_o      = (const float*)d_in[13];
  const float* ffn_w1   = (const float*)d_in[14];
  const float* ffn_w2   = (const float*)d_in[15];
  const float* ffn_w3   = (const float*)d_in[16];
  float* out = (float*)d_out;

  // ---- workspace layout ----
  float* ws   = (float*)d_ws;
  float* x    = ws;                          // 2097152 f32
  us*    hbf  = (us*)(x + 2097152);          // 2097152 us
  float* gk   = x + 2097152 + 1048576;
  float* nrm  = gk + 2048;                   // dead slot
  float* cosT = nrm + 2048;
  float* sinT = cosT + 32768;
  us*    MpBH = (us*)(sinT + 32768);         // H*DH*DH us
  float* h    = sinT + 32768 + 65536;        // dead slot (temb alias base)
  float* qkv  = h + 2097152;                 // dead slot
  us*    obf  = (us*)(qkv + 6291456);        // 2097152 us
  us*    qb   = obf + 2097152;
  us*    kb   = qb + 2097152;
  us*    vb   = kb + 2097152;
  us*    kbT  = vb + 2097152;
  us*    vbT  = kbT + 2097152;
  us*    f1bf = vbT + 2097152;               // M*FFP = 5636096 us
  us*    wq   = f1bf + (size_t)M*FFP;        // 3145728
  us*    wo   = wq + 3145728;                // 1048576
  us*    w1c  = wo + 1048576;                // 2795520
  us*    w2c  = w1c + 2795520;               // 2795520
  us*    w3c  = w2c + 2795520;               // 2818048
  us*    temb = (us*)h;                      // aliases dead h..f1bf span

  k_embed<<<M, 256, 0, stream>>>(ids, tok_emb, w_init, x);
  k_rope_tables<<<(S*32 + 255)/256, 256, 0, stream>>>(cosT, sinT);
  k_mp<<<H, 256, 0, stream>>>(persist, MpBH);

  for (int l = 0; l < NL; l++) {
    k_cvtw<<<2048, 256, 0, stream>>>(qkv_w + (size_t)l*3*D*D, w_o + (size_t)l*D*D,
                                     ffn_w1 + (size_t)l*FF*D, ffn_w2 + (size_t)l*FF*D,
                                     ffn_w3 + (size_t)l*D*FF,
                                     wq, wo, w1c, w2c, w3c);
    k_rmsg<<<M, 256, 0, stream>>>(x, norm1_w + (size_t)l * D,
                                  gamma_w1 + (size_t)l*GH*D, gamma_w2 + (size_t)l*GH,
                                  hbf, gk);
    k_pqkv<<<dim3(16, 24), 256, 0, stream>>>(hbf, wq,
                                             q_norm_w + (size_t)l*DH, k_norm_w + (size_t)l*DH,
                                             cosT, sinT, qb, kb, vb);
    k_tr2<<<dim3(S/64, B*H, 2), 256, 0, stream>>>(kb, vb, kbT, vbT);
    k_matt<<<dim3(8, B*H), 256, 0, stream>>>(qb, kb, kbT, vbT, MpBH, gk, mem_gate, l, obf);
    k_pgemm<2,64,64><<<dim3(M/64, D/64), 256, 0, stream>>>(obf, wo, x, D, D);
    k_rms<<<M, 256, 0, stream>>>(x, norm2_w + (size_t)l * D, hbf);
    k_pffn12<<<dim3(M/128, (FF+63)/64), 256, 0, stream>>>(hbf, w1c, w2c, f1bf, FF, D);
    k_pgemm<2,64,64><<<dim3(M/64, D/64), 256, 0, stream>>>(f1bf, w3c, x, D, FFP);
  }

  k_rms<<<M, 256, 0, stream>>>(x, norm_f_w, hbf);
  k_cvt<<<2048, 256, 0, stream>>>(tok_emb, temb, V*D);
  k_gemm8<<<dim3(8, V/256), 512, 0, stream>>>(hbf, temb, out, V, D);
}